// Round 16
// baseline (873.929 us; speedup 1.0000x reference)
//
#include <hip/hip_runtime.h>
#include <hip/hip_bf16.h>

#define M_TOK   8000
#define L_SEQ   2000
#define BATCH   4
#define NEXP    4
#define NH      16
#define HD      64
#define DSTATE  128
#define DMODEL  512
#define DINNER  1024
#define CONVD   1280
#define DIN_ALL 2320   // 1024 z + 1280 xBC + 16 dt
#define TCH     128    // SSD chunk length
#define NC      16     // chunks per sequence
#define LPAD    136    // LDS row pitch (shorts) for SSD tiles

typedef __attribute__((ext_vector_type(8))) short short8;
typedef __attribute__((ext_vector_type(4))) float f32x4;
typedef unsigned short u16;

__device__ __forceinline__ float siluf(float v) {
    return v / (1.f + __expf(-v));
}
__device__ __forceinline__ float softplusf(float v) {
    return v > 20.f ? v : log1pf(expf(v));
}
__device__ __forceinline__ u16 f2bf(float f) {
    union { float f; unsigned u; } x; x.f = f;
    return (u16)((x.u + 0x7fffu + ((x.u >> 16) & 1u)) >> 16);
}
__device__ __forceinline__ float bf2f(u16 v) {
    union { unsigned u; float f; } x; x.u = ((unsigned)v) << 16; return x.f;
}
__device__ __forceinline__ void gl16(const void* g, void* l) {
    __builtin_amdgcn_global_load_lds(
        (const __attribute__((address_space(1))) void*)g,
        (__attribute__((address_space(3))) void*)l, 16, 0, 0);
}

// ---------------------------------------------------------------- gating ----
__global__ void __launch_bounds__(64) gate_kernel(
    const float* __restrict__ X, const float* __restrict__ GW,
    const float* __restrict__ GB, const float* __restrict__ GN,
    float* __restrict__ mask)
{
    const int m = blockIdx.x;
    const int t = threadIdx.x;
    const float* x = X + (size_t)m * DMODEL;
    float s0 = 0.f, s1 = 0.f, s2 = 0.f, s3 = 0.f;
    for (int k = t; k < DMODEL; k += 64) {
        float xv = x[k];
        s0 += xv * GW[k];
        s1 += xv * GW[512 + k];
        s2 += xv * GW[1024 + k];
        s3 += xv * GW[1536 + k];
    }
    #pragma unroll
    for (int o = 32; o > 0; o >>= 1) {
        s0 += __shfl_down(s0, o);
        s1 += __shfl_down(s1, o);
        s2 += __shfl_down(s2, o);
        s3 += __shfl_down(s3, o);
    }
    if (t == 0) {
        float lg[4] = { s0 + GB[0] + GN[m*4+0]*0.01f,
                        s1 + GB[1] + GN[m*4+1]*0.01f,
                        s2 + GB[2] + GN[m*4+2]*0.01f,
                        s3 + GB[3] + GN[m*4+3]*0.01f };
        float mx = fmaxf(fmaxf(lg[0], lg[1]), fmaxf(lg[2], lg[3]));
        float p[4]; float sum = 0.f;
        #pragma unroll
        for (int e = 0; e < 4; ++e) { p[e] = expf(lg[e] - mx); sum += p[e]; }
        #pragma unroll
        for (int e = 0; e < 4; ++e) p[e] /= sum;
        int i0 = 0;
        #pragma unroll
        for (int e = 1; e < 4; ++e) if (p[e] > p[i0]) i0 = e;
        int i1 = -1;
        #pragma unroll
        for (int e = 0; e < 4; ++e) {
            if (e == i0) continue;
            if (i1 < 0 || p[e] > p[i1]) i1 = e;
        }
        float s2v = p[i0] + p[i1];
        #pragma unroll
        for (int e = 0; e < 4; ++e)
            mask[m*4 + e] = (e == i0 || e == i1) ? p[e] / s2v : 0.f;
    }
}

// ------------------------------------------------------- f32 -> bf16 copy ---
__global__ void __launch_bounds__(256) cvt_kernel(
    const float* __restrict__ src, u16* __restrict__ dst, int n8)
{
    const int i = blockIdx.x * 256 + threadIdx.x;
    if (i >= n8) return;
    const float4 a = ((const float4*)src)[i*2];
    const float4 b = ((const float4*)src)[i*2 + 1];
    short8 o;
    o[0]=f2bf(a.x); o[1]=f2bf(a.y); o[2]=f2bf(a.z); o[3]=f2bf(a.w);
    o[4]=f2bf(b.x); o[5]=f2bf(b.y); o[6]=f2bf(b.z); o[7]=f2bf(b.w);
    ((short8*)dst)[i] = o;
}

// -------------------- bf16 GEMM (8-wave, single-buffer, max occupancy) -----
// OUT[M x N] = A(bf16, M x K, stride lda) @ B(bf16, Nrows x K row-major)^T
// 128x128 tile, BK=64, 512 threads / 8 waves (wave owns 64x32 sub-tile),
// single 32KB LDS buffer -> 4 blocks/CU = 32 waves/CU (occupancy cap).
// MODE 0: OUT bf16, row stride ldo.
// MODE 2: OUT f32 512-stride, out (+)= mask[m*4+e]*acc.
// MODE 4: n<1280 -> OUT bf16 stride ldo; 1280<=n<1296 -> OUT2 f32 stride 16
//         = softplus(acc + bias[n-1280]).
template<int MODE>
__global__ void __launch_bounds__(512) gemm_bb(
    const u16* __restrict__ A, int lda, int Mrows,
    const u16* __restrict__ B, int K, int Nrows,
    void* __restrict__ OUT, int ldo,
    const float* __restrict__ mask, int e, int first,
    float* __restrict__ OUT2, const float* __restrict__ bias)
{
    __shared__ u16 As[128][64];
    __shared__ u16 Bs[128][64];
    const int t  = threadIdx.x;
    // XCD-aware bijective block swizzle (m204)
    const int nbx = gridDim.x;
    const int nwg = nbx * gridDim.y;
    int bid = blockIdx.y * nbx + blockIdx.x;
    {
        const int xcd = bid & 7, lo = bid >> 3;
        const int q8 = nwg >> 3, r8 = nwg & 7;
        bid = (xcd < r8 ? xcd*(q8+1) : r8*(q8+1) + (xcd - r8)*q8) + lo;
    }
    const int m0 = (bid / nbx) * 128;
    const int n0 = (bid % nbx) * 128;
    const int w  = t >> 6, l = t & 63;
    const int wm = (w >> 2) * 64, wn = (w & 3) * 32;
    const int sr = l >> 3;           // 0..7 (row within 8-row chunk)
    const int sc = (l & 7) * 8;      // bf16 col 0..56

    f32x4 acc[4][2];
    #pragma unroll
    for (int i = 0; i < 4; ++i)
        #pragma unroll
        for (int j = 0; j < 2; ++j) {
            acc[i][j][0]=0.f; acc[i][j][1]=0.f; acc[i][j][2]=0.f; acc[i][j][3]=0.f;
        }

    for (int k0 = 0; k0 < K; k0 += 64) {
        #pragma unroll
        for (int c = 0; c < 2; ++c) {
            const int row = c*64 + w*8;      // wave-uniform chunk base row
            int ga = m0 + row + sr; if (ga >= Mrows) ga = Mrows - 1;
            gl16(A + (size_t)ga*lda + k0 + sc, &As[row][0]);
            int gb = n0 + row + sr; if (gb >= Nrows) gb = Nrows - 1;
            gl16(B + (size_t)gb*K + k0 + sc, &Bs[row][0]);
        }
        __syncthreads();
        #pragma unroll
        for (int ks = 0; ks < 2; ++ks) {
            short8 af[4], bf[2];
            const int ko = ks*32 + (l >> 4)*8;
            #pragma unroll
            for (int i = 0; i < 4; ++i)
                af[i] = *(const short8*)&As[wm + i*16 + (l & 15)][ko];
            #pragma unroll
            for (int j = 0; j < 2; ++j)
                bf[j] = *(const short8*)&Bs[wn + j*16 + (l & 15)][ko];
            #pragma unroll
            for (int i = 0; i < 4; ++i)
                #pragma unroll
                for (int j = 0; j < 2; ++j)
                    acc[i][j] = __builtin_amdgcn_mfma_f32_16x16x32_bf16(
                        af[i], bf[j], acc[i][j], 0, 0, 0);
        }
        __syncthreads();
    }

    #pragma unroll
    for (int i = 0; i < 4; ++i) {
        #pragma unroll
        for (int r = 0; r < 4; ++r) {
            const int m = m0 + wm + i*16 + (l >> 4)*4 + r;
            if (m >= Mrows) continue;
            if (MODE == 2) {
                const float wgt = mask[m*4 + e];
                #pragma unroll
                for (int j = 0; j < 2; ++j) {
                    const int n = n0 + wn + j*16 + (l & 15);
                    float* o = (float*)OUT + (size_t)m*512 + n;
                    const float v = wgt * acc[i][j][r];
                    *o = first ? v : *o + v;
                }
            } else if (MODE == 4) {
                #pragma unroll
                for (int j = 0; j < 2; ++j) {
                    const int n = n0 + wn + j*16 + (l & 15);
                    if (n < CONVD) {
                        ((u16*)OUT)[(size_t)m*ldo + n] = f2bf(acc[i][j][r]);
                    } else if (n < CONVD + NH) {
                        OUT2[(size_t)m*NH + (n - CONVD)] =
                            softplusf(acc[i][j][r] + bias[n - CONVD]);
                    }
                }
            } else {
                #pragma unroll
                for (int j = 0; j < 2; ++j) {
                    const int n = n0 + wn + j*16 + (l & 15);
                    ((u16*)OUT)[(size_t)m*ldo + n] = f2bf(acc[i][j][r]);
                }
            }
        }
    }
}

// ---------------------------------------- conv4 + SiLU, direct (no LDS) -----
__global__ void __launch_bounds__(256) conv_kernel(
    const u16* __restrict__ XBC,     // M x 1280 bf16 raw
    u16* __restrict__ XCONV,         // M x 1280 bf16
    const float* __restrict__ conv_w,
    const float* __restrict__ conv_b,
    int eg)
{
    const int idx = blockIdx.x * 256 + threadIdx.x;
    const int NCG = CONVD / 8;                  // 160
    if (idx >= M_TOK * NCG) return;
    const int cg = idx % NCG;
    const int m  = idx / NCG;
    const int b  = m / L_SEQ, l = m - b*L_SEQ;
    const int c0 = cg * 8;

    const u16* base = XBC + (size_t)b*L_SEQ*CONVD + c0;
    const short8 z8 = {0,0,0,0,0,0,0,0};
    short8 r[4];
    #pragma unroll
    for (int k = 0; k < 4; ++k) {
        const int row = l - 3 + k;
        r[k] = (row >= 0) ? *(const short8*)(base + (size_t)row*CONVD) : z8;
    }
    const float4* wp = (const float4*)(conv_w + ((size_t)eg*CONVD + c0)*4);
    const float*  bp = conv_b + (size_t)eg*CONVD + c0;
    short8 o;
    #pragma unroll
    for (int j = 0; j < 8; ++j) {
        const float4 wj = wp[j];
        float v = bf2f(r[0][j])*wj.x + bf2f(r[1][j])*wj.y
                + bf2f(r[2][j])*wj.z + bf2f(r[3][j])*wj.w + bp[j];
        o[j] = f2bf(siluf(v));
    }
    *(short8*)(XCONV + (size_t)m*CONVD + c0) = o;
}

// --------------------------------------------------- SSD pass 1 (per chunk) -
// Round-7 math (dense S, __expf, separate Pb) at 1024 threads / 16 waves:
// wave w -> S row-tile rt=w>>1, col-half ch=w&1; Y1/Hloc split pt by ch.
__global__ void __launch_bounds__(1024) ssd1_kernel(
    u16* __restrict__ XCONV,
    const float* __restrict__ DT,
    float* __restrict__ Acum,          // bh x 2000 (natural-log units)
    u16* __restrict__ Hend,            // (bh*NC+g) x 128 x 64
    float* __restrict__ cbuf,          // bh*NC+g
    const float* __restrict__ A_log,
    const float* __restrict__ Dskip,
    int eg)
{
    const int g = blockIdx.x, h = blockIdx.y, b = blockIdx.z;
    const int t = threadIdx.x;
    const int ln = t & 63, w = t >> 6;     // 16 waves
    const int rt = w >> 1;                 // S row-tile 0..7
    const int ch = w & 1;                  // column half
    const int bh = b*NH + h;
    const int l0 = g * TCH;

    __shared__ u16 Bc[TCH][LPAD];
    __shared__ u16 Cc[TCH][LPAD];
    __shared__ u16 Xt[HD][LPAD];
    __shared__ u16 Pb[TCH][LPAD];
    __shared__ float ac[TCH], wj[TCH], dtb[TCH];

    const float Ah = -__expf(A_log[eg*NH + h]);
    const float Dv = Dskip[eg*NH + h];

    {   // stage: 8 threads per row (i = t>>3), 16 cols each for B/C, 8 for x
        const int i = t >> 3, q = t & 7;
        const bool v = (l0 + i) < L_SEQ;
        const u16* src = XCONV + (size_t)(b*L_SEQ + l0 + i) * CONVD;
        const short8 z8 = {0,0,0,0,0,0,0,0};
        #pragma unroll
        for (int u = 0; u < 2; ++u) {
            const int col = q*16 + u*8;
            short8 bv = v ? *(const short8*)(src + 1024 + col) : z8;
            short8 cv = v ? *(const short8*)(src + 1152 + col) : z8;
            *(short8*)&Bc[i][col] = bv;
            *(short8*)&Cc[i][col] = cv;
        }
        {
            short8 xv = v ? *(const short8*)(src + h*HD + q*8) : z8;
            #pragma unroll
            for (int k = 0; k < 8; ++k)
                Xt[q*8 + k][i] = ((const u16*)&xv)[k];
        }
        if (t < TCH) {
            const int l = l0 + t;
            dtb[t] = (l < L_SEQ) ? DT[(size_t)(b*L_SEQ + l)*NH + h] : 0.f;
        }
    }
    __syncthreads();

    if (w == 0) {
        float s0 = dtb[ln] * Ah;
        float s1 = dtb[64 + ln] * Ah;
        #pragma unroll
        for (int o = 1; o < 64; o <<= 1) {
            float v0 = __shfl_up(s0, o);
            float v1 = __shfl_up(s1, o);
            if (ln >= o) { s0 += v0; s1 += v1; }
        }
        s1 += __shfl(s0, 63);
        const float acT = __shfl(s1, 63);
        ac[ln] = s0; ac[64 + ln] = s1;
        wj[ln]      = __expf(acT - s0) * dtb[ln];
        wj[64 + ln] = __expf(acT - s1) * dtb[64 + ln];
        if (l0 + ln < L_SEQ)      Acum[(size_t)bh*L_SEQ + l0 + ln] = s0;
        if (l0 + 64 + ln < L_SEQ) Acum[(size_t)bh*L_SEQ + l0 + 64 + ln] = s1;
        if (ln == 63) cbuf[bh*NC + g] = __expf(acT);
    }
    __syncthreads();

    // S = Cc @ Bc^T: wave covers row-tile rt, col-tiles ch*4..ch*4+4
    f32x4 sacc[4];
    #pragma unroll
    for (int c = 0; c < 4; ++c) { sacc[c][0]=0.f; sacc[c][1]=0.f; sacc[c][2]=0.f; sacc[c][3]=0.f; }
    #pragma unroll
    for (int ks = 0; ks < 4; ++ks) {
        short8 afr = *(const short8*)&Cc[rt*16 + (ln & 15)][ks*32 + (ln >> 4)*8];
        #pragma unroll
        for (int c = 0; c < 4; ++c) {
            const int ct = ch*4 + c;
            short8 bfr = *(const short8*)&Bc[ct*16 + (ln & 15)][ks*32 + (ln >> 4)*8];
            sacc[c] = __builtin_amdgcn_mfma_f32_16x16x32_bf16(afr, bfr, sacc[c], 0, 0, 0);
        }
    }
    // P = mask(j<=i) * S * exp(ac_i - ac_j) * dt_j
    {
        const int i0 = rt*16 + (ln >> 4)*4;
        float aci[4];
        #pragma unroll
        for (int r = 0; r < 4; ++r) aci[r] = ac[i0 + r];
        #pragma unroll
        for (int c = 0; c < 4; ++c) {
            const int j = (ch*4 + c)*16 + (ln & 15);
            const float acj = ac[j], dtj = dtb[j];
            #pragma unroll
            for (int r = 0; r < 4; ++r) {
                const int i2 = i0 + r;
                float pv = (j <= i2) ? sacc[c][r] * __expf(aci[r] - acj) * dtj : 0.f;
                Pb[i2][j] = f2bf(pv);
            }
        }
    }
    __syncthreads();

    // Y1 = P @ X (+ D*x): wave covers row-tile rt, pt in {ch*2, ch*2+1}
    {
        f32x4 yacc[2];
        #pragma unroll
        for (int p = 0; p < 2; ++p) { yacc[p][0]=0.f; yacc[p][1]=0.f; yacc[p][2]=0.f; yacc[p][3]=0.f; }
        #pragma unroll
        for (int ks = 0; ks < 4; ++ks) {
            short8 afr = *(const short8*)&Pb[rt*16 + (ln & 15)][ks*32 + (ln >> 4)*8];
            #pragma unroll
            for (int p = 0; p < 2; ++p) {
                const int pt = ch*2 + p;
                short8 bfr = *(const short8*)&Xt[pt*16 + (ln & 15)][ks*32 + (ln >> 4)*8];
                yacc[p] = __builtin_amdgcn_mfma_f32_16x16x32_bf16(afr, bfr, yacc[p], 0, 0, 0);
            }
        }
        #pragma unroll
        for (int p = 0; p < 2; ++p) {
            const int pp = (ch*2 + p)*16 + (ln & 15);
            #pragma unroll
            for (int r = 0; r < 4; ++r) {
                const int i2 = rt*16 + (ln >> 4)*4 + r;
                const int lg = l0 + i2;
                if (lg < L_SEQ) {
                    const float xv = bf2f(Xt[pp][i2]);
                    XCONV[(size_t)(b*L_SEQ + lg)*CONVD + h*HD + pp] =
                        f2bf(yacc[p][r] + Dv * xv);
                }
            }
        }
    }

    // Hloc = (Bc^T * wj) @ X: wave covers n-tile rt, pt in {ch*2, ch*2+1}
    {
        f32x4 hacc[2];
        #pragma unroll
        for (int p = 0; p < 2; ++p) { hacc[p][0]=0.f; hacc[p][1]=0.f; hacc[p][2]=0.f; hacc[p][3]=0.f; }
        #pragma unroll
        for (int ks = 0; ks < 4; ++ks) {
            const int jb = ks*32 + (ln >> 4)*8;
            const int nr = rt*16 + (ln & 15);
            short8 afr;
            #pragma unroll
            for (int jj = 0; jj < 8; ++jj)
                afr[jj] = (short)f2bf(bf2f(Bc[jb + jj][nr]) * wj[jb + jj]);
            #pragma unroll
            for (int p = 0; p < 2; ++p) {
                const int pt = ch*2 + p;
                short8 bfr = *(const short8*)&Xt[pt*16 + (ln & 15)][jb];
                hacc[p] = __builtin_amdgcn_mfma_f32_16x16x32_bf16(afr, bfr, hacc[p], 0, 0, 0);
            }
        }
        u16* Hb = Hend + (size_t)(bh*NC + g) * (TCH*HD);
        #pragma unroll
        for (int p = 0; p < 2; ++p)
            #pragma unroll
            for (int r = 0; r < 4; ++r) {
                const int n = rt*16 + (ln >> 4)*4 + r;
                Hb[n*HD + (ch*2 + p)*16 + (ln & 15)] = f2bf(hacc[p][r]);
            }
    }
}

// --------------------------------------- pass 2: chunk-state propagation ----
__global__ void __launch_bounds__(256) prop_kernel(
    u16* __restrict__ Hend, const float* __restrict__ cbuf)
{
    const int bh = blockIdx.x;
    const int t  = threadIdx.x;
    float hs[32];
    #pragma unroll
    for (int j = 0; j < 32; ++j) hs[j] = 0.f;
    for (int g = 0; g < NC - 1; ++g) {
        const float ce = cbuf[bh*NC + g];
        u16* He = Hend + (size_t)(bh*NC + g)*(TCH*HD) + t*32;
        #pragma unroll
        for (int j = 0; j < 32; ++j) {
            const float lo = bf2f(He[j]);
            hs[j] = ce*hs[j] + lo;
            He[j] = f2bf(hs[j]);
        }
    }
}

// --------------------------------------------- pass 3: Y2 = Cs @ h_start ----
__global__ void __launch_bounds__(256) ssd2_kernel(
    u16* __restrict__ XCONV,
    const float* __restrict__ Acum,    // natural-log units
    const u16* __restrict__ Hend)
{
    const int g = blockIdx.x + 1, h = blockIdx.y, b = blockIdx.z;
    const int t = threadIdx.x, ln = t & 63, w = t >> 6;
    const int bh = b*NH + h;
    const int l0 = g * TCH;

    __shared__ u16 Cs[TCH][LPAD];
    __shared__ u16 Ht[HD][LPAD];

    {
        const int i = t >> 1, q = t & 1;
        const bool v = (l0 + i) < L_SEQ;
        const float eaci = v ? __expf(Acum[(size_t)bh*L_SEQ + l0 + i]) : 0.f;
        const u16* src = XCONV + (size_t)(b*L_SEQ + l0 + i)*CONVD + 1152 + q*64;
        const short8 z8 = {0,0,0,0,0,0,0,0};
        #pragma unroll
        for (int u = 0; u < 8; ++u) {
            short8 cv = v ? *(const short8*)(src + u*8) : z8;
            short8 ov;
            #pragma unroll
            for (int k = 0; k < 8; ++k)
                ov[k] = (short)f2bf(bf2f(((const u16*)&cv)[k]) * eaci);
            *(short8*)&Cs[i][q*64 + u*8] = ov;
        }
    }
    {
        const u16* Hb = Hend + (size_t)(bh*NC + g - 1)*(TCH*HD) + t*32;
        #pragma unroll
        for (int k = 0; k < 32; ++k) {
            const int idx = t*32 + k;
            Ht[idx & 63][idx >> 6] = Hb[k];
        }
    }
    __syncthreads();

    f32x4 acc2[2][4];
    #pragma unroll
    for (int rt = 0; rt < 2; ++rt)
        #pragma unroll
        for (int pt = 0; pt < 4; ++pt) { acc2[rt][pt][0]=0.f; acc2[rt][pt][1]=0.f; acc2[rt][pt][2]=0.f; acc2[rt][pt][3]=0.f; }
    #pragma unroll
    for (int ks = 0; ks < 4; ++ks) {
        short8 af0 = *(const short8*)&Cs[w*32 +      (ln & 15)][ks*32 + (ln >> 4)*8];
        short8 af1 = *(const short8*)&Cs[w*32 + 16 + (ln & 15)][ks*32 + (ln >> 4)*8];
        #pragma unroll
        for (int pt = 0; pt < 4; ++pt) {
            short8 bfr = *(const short8*)&Ht[pt*16 + (ln & 15)][ks*32 + (ln >> 4)*8];
            acc2[0][pt] = __builtin_amdgcn_mfma_f32_16x16x32_bf16(af0, bfr, acc2[0][pt], 0, 0, 0);
            acc2[1][pt] = __builtin_amdgcn_mfma_f32_16x16x32_bf16(af1, bfr, acc2[1][pt], 0, 0, 0);
        }
    }
    #pragma unroll
    for (int rt = 0; rt < 2; ++rt)
        #pragma unroll
        for (int pt = 0; pt < 4; ++pt)
            #pragma unroll
            for (int r = 0; r < 4; ++r) {
                const int i2 = w*32 + rt*16 + (ln >> 4)*4 + r;
                const int lg = l0 + i2;
                if (lg < L_SEQ) {
                    u16* yp = XCONV + (size_t)(b*L_SEQ + lg)*CONVD + h*HD + pt*16 + (ln & 15);
                    *yp = f2bf(bf2f(*yp) + acc2[rt][pt][r]);
                }
            }
}

// ------------------------------------------------- gated RMS norm (bf16) ----
__global__ void __launch_bounds__(256) norm_kernel(
    u16* __restrict__ Ybuf,            // rows, stride 1280 (bf16), in-place
    const u16* __restrict__ Z,         // rows x 1024 bf16
    const float* __restrict__ nw)      // 1024
{
    const int row = blockIdx.x;
    const int t = threadIdx.x;
    u16* y = Ybuf + (size_t)row * CONVD;
    const u16* z = Z + (size_t)row * DINNER;

    ushort4 yv = *(const ushort4*)(y + t*4);
    ushort4 zv = *(const ushort4*)(z + t*4);
    float v[4]; float ss = 0.f;
    #pragma unroll
    for (int j = 0; j < 4; ++j) {
        const float zz = bf2f(((const u16*)&zv)[j]);
        const float vv = bf2f(((const u16*)&yv)[j]) * siluf(zz);
        v[j] = vv; ss += vv*vv;
    }
    #pragma unroll
    for (int o = 32; o > 0; o >>= 1) ss += __shfl_down(ss, o);
    __shared__ float wsum[4];
    if ((t & 63) == 0) wsum[t >> 6] = ss;
    __syncthreads();
    const float total = wsum[0] + wsum[1] + wsum[2] + wsum[3];
    const float scale = rsqrtf(total / (float)DINNER + 1e-5f);
    ushort4 ov;
    #pragma unroll
    for (int j = 0; j < 4; ++j)
        ((u16*)&ov)[j] = f2bf(v[j] * scale * nw[t*4 + j]);
    *(ushort4*)(y + t*4) = ov;
}

// ------------------------------------------------------------------ host ----
extern "C" void kernel_launch(void* const* d_in, const int* in_sizes, int n_in,
                              void* d_out, int out_size, void* d_ws, size_t ws_size,
                              hipStream_t stream)
{
    const float* x        = (const float*)d_in[0];
    const float* gate_w   = (const float*)d_in[1];
    const float* gate_b   = (const float*)d_in[2];
    const float* gate_n   = (const float*)d_in[3];
    const float* in_w     = (const float*)d_in[4];
    const float* conv_w   = (const float*)d_in[5];
    const float* conv_b   = (const float*)d_in[6];
    const float* dt_bias  = (const float*)d_in[7];
    const float* A_log    = (const float*)d_in[8];
    const float* Dskip    = (const float*)d_in[9];
    const float* norm_w   = (const float*)d_in[10];
    const float* out_w    = (const float*)d_in[11];
    float* out = (float*)d_out;

    char* ws = (char*)d_ws;
    // R1 serves sequentially: XBCraw bf16 (gemm->conv) -> Hend (ssd1->ssd2)
    //                         -> Ztile bf16 full-M (z-gemm->norm)
    u16*   R1     = (u16*)ws;                        // 20,480,000 B
    u16*   XCONV  = (u16*)(ws + 20480000);           // 20,480,000 B
    u16*   xbf    = (u16*)(ws + 40960000);           //  8,192,000 B
    u16*   inwb   = (u16*)(ws + 49152000);           //  9,502,720 B (4x2320x512)
    u16*   outwb  = (u16*)(ws + 58654720);           //  4,194,304 B
    float* DTb    = (float*)(ws + 62849024);         //    512,000 B
    float* Acum   = (float*)(ws + 63361024);         //    512,000 B
    float* cbuf   = (float*)(ws + 63873024);         //      4,096 B
    float* maskb  = (float*)(ws + 63877120);         //    128,000 B
    // total 64,005,120 B (< 74.36 MB proven-safe)

    gate_kernel<<<M_TOK, 64, 0, stream>>>(x, gate_w, gate_b, gate_n, maskb);
    // one-time bf16 conversions
    cvt_kernel<<<2000, 256, 0, stream>>>(x, xbf, 512000);
    for (int e = 0; e < NEXP; ++e)
        cvt_kernel<<<580, 256, 0, stream>>>(
            in_w + (size_t)e*DIN_ALL*DMODEL, inwb + (size_t)e*DIN_ALL*512, 148480);
    cvt_kernel<<<1024, 256, 0, stream>>>(out_w, outwb, 262144);

    for (int e = 0; e < NEXP; ++e) {
        const u16* Wxbcdt = inwb + (size_t)e*DIN_ALL*512 + (size_t)1024*512;
        const u16* Wz     = inwb + (size_t)e*DIN_ALL*512;
        // raw xBC (bf16) + dt (f32 softplus) fused
        gemm_bb<4><<<dim3(11, 63), 512, 0, stream>>>(
            xbf, DMODEL, M_TOK, Wxbcdt, DMODEL, 1296,
            R1, CONVD, nullptr, 0, 0, DTb, dt_bias + e*NH);
        conv_kernel<<<5000, 256, 0, stream>>>(R1, XCONV, conv_w, conv_b, e);
        ssd1_kernel<<<dim3(NC, NH, BATCH), 1024, 0, stream>>>(
            XCONV, DTb, Acum, (u16*)R1, cbuf, A_log, Dskip, e);
        prop_kernel<<<BATCH*NH, 256, 0, stream>>>((u16*)R1, cbuf);
        ssd2_kernel<<<dim3(NC - 1, NH, BATCH), 256, 0, stream>>>(
            XCONV, Acum, (const u16*)R1);
        // z (bf16, full M) into R1 (Hend now dead)
        gemm_bb<0><<<dim3(8, 63), 512, 0, stream>>>(
            xbf, DMODEL, M_TOK, Wz, DMODEL, DINNER,
            R1, DINNER, nullptr, 0, 0, nullptr, nullptr);
        norm_kernel<<<M_TOK, 256, 0, stream>>>(
            XCONV, R1, norm_w + (size_t)e*DINNER);
        gemm_bb<2><<<dim3(4, 63), 512, 0, stream>>>(
            XCONV, CONVD, M_TOK, outwb + (size_t)e*DMODEL*DINNER, DINNER, DMODEL,
            out, 512, maskb, e, e == 0 ? 1 : 0, nullptr, nullptr);
    }
}

// Round 17
// 848.695 us; speedup vs baseline: 1.0297x; 1.0297x over previous
//
#include <hip/hip_runtime.h>
#include <hip/hip_bf16.h>

#define M_TOK   8000
#define L_SEQ   2000
#define BATCH   4
#define NEXP    4
#define NH      16
#define HD      64
#define DSTATE  128
#define DMODEL  512
#define DINNER  1024
#define CONVD   1280
#define DIN_ALL 2320   // 1024 z + 1280 xBC + 16 dt
#define TCH     128    // SSD chunk length
#define NC      16     // chunks per sequence
#define LPAD    136    // LDS row pitch (shorts) for SSD tiles

typedef __attribute__((ext_vector_type(8))) short short8;
typedef __attribute__((ext_vector_type(4))) float f32x4;
typedef unsigned short u16;

__device__ __forceinline__ float siluf(float v) {
    return v / (1.f + __expf(-v));
}
__device__ __forceinline__ float softplusf(float v) {
    return v > 20.f ? v : log1pf(expf(v));
}
__device__ __forceinline__ u16 f2bf(float f) {
    union { float f; unsigned u; } x; x.f = f;
    return (u16)((x.u + 0x7fffu + ((x.u >> 16) & 1u)) >> 16);
}
__device__ __forceinline__ float bf2f(u16 v) {
    union { unsigned u; float f; } x; x.u = ((unsigned)v) << 16; return x.f;
}
__device__ __forceinline__ void gl16(const void* g, void* l) {
    __builtin_amdgcn_global_load_lds(
        (const __attribute__((address_space(1))) void*)g,
        (__attribute__((address_space(3))) void*)l, 16, 0, 0);
}

// ---------------------------------------------------------------- gating ----
__global__ void __launch_bounds__(64) gate_kernel(
    const float* __restrict__ X, const float* __restrict__ GW,
    const float* __restrict__ GB, const float* __restrict__ GN,
    float* __restrict__ mask)
{
    const int m = blockIdx.x;
    const int t = threadIdx.x;
    const float* x = X + (size_t)m * DMODEL;
    float s0 = 0.f, s1 = 0.f, s2 = 0.f, s3 = 0.f;
    for (int k = t; k < DMODEL; k += 64) {
        float xv = x[k];
        s0 += xv * GW[k];
        s1 += xv * GW[512 + k];
        s2 += xv * GW[1024 + k];
        s3 += xv * GW[1536 + k];
    }
    #pragma unroll
    for (int o = 32; o > 0; o >>= 1) {
        s0 += __shfl_down(s0, o);
        s1 += __shfl_down(s1, o);
        s2 += __shfl_down(s2, o);
        s3 += __shfl_down(s3, o);
    }
    if (t == 0) {
        float lg[4] = { s0 + GB[0] + GN[m*4+0]*0.01f,
                        s1 + GB[1] + GN[m*4+1]*0.01f,
                        s2 + GB[2] + GN[m*4+2]*0.01f,
                        s3 + GB[3] + GN[m*4+3]*0.01f };
        float mx = fmaxf(fmaxf(lg[0], lg[1]), fmaxf(lg[2], lg[3]));
        float p[4]; float sum = 0.f;
        #pragma unroll
        for (int e = 0; e < 4; ++e) { p[e] = expf(lg[e] - mx); sum += p[e]; }
        #pragma unroll
        for (int e = 0; e < 4; ++e) p[e] /= sum;
        int i0 = 0;
        #pragma unroll
        for (int e = 1; e < 4; ++e) if (p[e] > p[i0]) i0 = e;
        int i1 = -1;
        #pragma unroll
        for (int e = 0; e < 4; ++e) {
            if (e == i0) continue;
            if (i1 < 0 || p[e] > p[i1]) i1 = e;
        }
        float s2v = p[i0] + p[i1];
        #pragma unroll
        for (int e = 0; e < 4; ++e)
            mask[m*4 + e] = (e == i0 || e == i1) ? p[e] / s2v : 0.f;
    }
}

// ------------------------------------------------------- f32 -> bf16 copy ---
__global__ void __launch_bounds__(256) cvt_kernel(
    const float* __restrict__ src, u16* __restrict__ dst, int n8)
{
    const int i = blockIdx.x * 256 + threadIdx.x;
    if (i >= n8) return;
    const float4 a = ((const float4*)src)[i*2];
    const float4 b = ((const float4*)src)[i*2 + 1];
    short8 o;
    o[0]=f2bf(a.x); o[1]=f2bf(a.y); o[2]=f2bf(a.z); o[3]=f2bf(a.w);
    o[4]=f2bf(b.x); o[5]=f2bf(b.y); o[6]=f2bf(b.z); o[7]=f2bf(b.w);
    ((short8*)dst)[i] = o;
}

// --------------------------- bf16 GEMM (8-wave, 2-phase double-buffered) ----
// OUT[M x N] = A(bf16, M x K, stride lda) @ B(bf16, Nrows x K row-major)^T
// 128x128 tile, BK=64, 512 threads / 8 waves (wave owns 64x32 sub-tile),
// global_load_lds dbuf staging, one barrier per K-iter, XCD-swizzled grid.
// MODE 0: OUT bf16, row stride ldo.
// MODE 2: OUT f32 512-stride, out (+)= mask[m*4+e]*acc.
// MODE 4: n<1280 -> OUT bf16 stride ldo; 1280<=n<1296 -> OUT2 f32 stride 16
//         = softplus(acc + bias[n-1280]).
template<int MODE>
__global__ void __launch_bounds__(512) gemm_bb(
    const u16* __restrict__ A, int lda, int Mrows,
    const u16* __restrict__ B, int K, int Nrows,
    void* __restrict__ OUT, int ldo,
    const float* __restrict__ mask, int e, int first,
    float* __restrict__ OUT2, const float* __restrict__ bias)
{
    __shared__ u16 As[2][128][64];
    __shared__ u16 Bs[2][128][64];
    const int t  = threadIdx.x;
    // XCD-aware bijective block swizzle (m204)
    const int nbx = gridDim.x;
    const int nwg = nbx * gridDim.y;
    int bid = blockIdx.y * nbx + blockIdx.x;
    {
        const int xcd = bid & 7, lo = bid >> 3;
        const int q8 = nwg >> 3, r8 = nwg & 7;
        bid = (xcd < r8 ? xcd*(q8+1) : r8*(q8+1) + (xcd - r8)*q8) + lo;
    }
    const int m0 = (bid / nbx) * 128;
    const int n0 = (bid % nbx) * 128;
    const int w  = t >> 6, l = t & 63;
    const int wm = (w >> 2) * 64, wn = (w & 3) * 32;
    const int sr = l >> 3;           // 0..7 (row within 8-row chunk)
    const int sc = (l & 7) * 8;      // bf16 col 0..56

    f32x4 acc[4][2];
    #pragma unroll
    for (int i = 0; i < 4; ++i)
        #pragma unroll
        for (int j = 0; j < 2; ++j) {
            acc[i][j][0]=0.f; acc[i][j][1]=0.f; acc[i][j][2]=0.f; acc[i][j][3]=0.f;
        }

    const int nk = K >> 6;
    // prologue: stage tile 0 into buffer 0
    #pragma unroll
    for (int c = 0; c < 2; ++c) {
        const int row = c*64 + w*8;      // wave-uniform chunk base row
        int ga = m0 + row + sr; if (ga >= Mrows) ga = Mrows - 1;
        gl16(A + (size_t)ga*lda + sc, &As[0][row][0]);
        int gb = n0 + row + sr; if (gb >= Nrows) gb = Nrows - 1;
        gl16(B + (size_t)gb*K + sc, &Bs[0][row][0]);
    }
    __syncthreads();

    for (int kt = 0; kt < nk; ++kt) {
        const int cur = kt & 1;
        if (kt + 1 < nk) {
            const int nxt = cur ^ 1;
            const int k0 = (kt + 1) << 6;
            #pragma unroll
            for (int c = 0; c < 2; ++c) {
                const int row = c*64 + w*8;
                int ga = m0 + row + sr; if (ga >= Mrows) ga = Mrows - 1;
                gl16(A + (size_t)ga*lda + k0 + sc, &As[nxt][row][0]);
                int gb = n0 + row + sr; if (gb >= Nrows) gb = Nrows - 1;
                gl16(B + (size_t)gb*K + k0 + sc, &Bs[nxt][row][0]);
            }
        }
        #pragma unroll
        for (int ks = 0; ks < 2; ++ks) {
            short8 af[4], bf[2];
            const int ko = ks*32 + (l >> 4)*8;
            #pragma unroll
            for (int i = 0; i < 4; ++i)
                af[i] = *(const short8*)&As[cur][wm + i*16 + (l & 15)][ko];
            #pragma unroll
            for (int j = 0; j < 2; ++j)
                bf[j] = *(const short8*)&Bs[cur][wn + j*16 + (l & 15)][ko];
            #pragma unroll
            for (int i = 0; i < 4; ++i)
                #pragma unroll
                for (int j = 0; j < 2; ++j)
                    acc[i][j] = __builtin_amdgcn_mfma_f32_16x16x32_bf16(
                        af[i], bf[j], acc[i][j], 0, 0, 0);
        }
        __syncthreads();   // next-tile loads landed during MFMA
    }

    #pragma unroll
    for (int i = 0; i < 4; ++i) {
        #pragma unroll
        for (int r = 0; r < 4; ++r) {
            const int m = m0 + wm + i*16 + (l >> 4)*4 + r;
            if (m >= Mrows) continue;
            if (MODE == 2) {
                const float wgt = mask[m*4 + e];
                #pragma unroll
                for (int j = 0; j < 2; ++j) {
                    const int n = n0 + wn + j*16 + (l & 15);
                    float* o = (float*)OUT + (size_t)m*512 + n;
                    const float v = wgt * acc[i][j][r];
                    *o = first ? v : *o + v;
                }
            } else if (MODE == 4) {
                #pragma unroll
                for (int j = 0; j < 2; ++j) {
                    const int n = n0 + wn + j*16 + (l & 15);
                    if (n < CONVD) {
                        ((u16*)OUT)[(size_t)m*ldo + n] = f2bf(acc[i][j][r]);
                    } else if (n < CONVD + NH) {
                        OUT2[(size_t)m*NH + (n - CONVD)] =
                            softplusf(acc[i][j][r] + bias[n - CONVD]);
                    }
                }
            } else {
                #pragma unroll
                for (int j = 0; j < 2; ++j) {
                    const int n = n0 + wn + j*16 + (l & 15);
                    ((u16*)OUT)[(size_t)m*ldo + n] = f2bf(acc[i][j][r]);
                }
            }
        }
    }
}

// ---------------------------------------- conv4 + SiLU, direct (no LDS) -----
__global__ void __launch_bounds__(256) conv_kernel(
    const u16* __restrict__ XBC,     // M x 1280 bf16 raw
    u16* __restrict__ XCONV,         // M x 1280 bf16
    const float* __restrict__ conv_w,
    const float* __restrict__ conv_b,
    int eg)
{
    const int idx = blockIdx.x * 256 + threadIdx.x;
    const int NCG = CONVD / 8;                  // 160
    if (idx >= M_TOK * NCG) return;
    const int cg = idx % NCG;
    const int m  = idx / NCG;
    const int b  = m / L_SEQ, l = m - b*L_SEQ;
    const int c0 = cg * 8;

    const u16* base = XBC + (size_t)b*L_SEQ*CONVD + c0;
    const short8 z8 = {0,0,0,0,0,0,0,0};
    short8 r[4];
    #pragma unroll
    for (int k = 0; k < 4; ++k) {
        const int row = l - 3 + k;
        r[k] = (row >= 0) ? *(const short8*)(base + (size_t)row*CONVD) : z8;
    }
    const float4* wp = (const float4*)(conv_w + ((size_t)eg*CONVD + c0)*4);
    const float*  bp = conv_b + (size_t)eg*CONVD + c0;
    short8 o;
    #pragma unroll
    for (int j = 0; j < 8; ++j) {
        const float4 wj = wp[j];
        float v = bf2f(r[0][j])*wj.x + bf2f(r[1][j])*wj.y
                + bf2f(r[2][j])*wj.z + bf2f(r[3][j])*wj.w + bp[j];
        o[j] = f2bf(siluf(v));
    }
    *(short8*)(XCONV + (size_t)m*CONVD + c0) = o;
}

// --------------------------------------------------- SSD pass 1 (per chunk) -
// Round-7 math (dense S, __expf, separate Pb) at 1024 threads / 16 waves:
// wave w -> S row-tile rt=w>>1, col-half ch=w&1; Y1/Hloc split pt by ch.
__global__ void __launch_bounds__(1024) ssd1_kernel(
    u16* __restrict__ XCONV,
    const float* __restrict__ DT,
    float* __restrict__ Acum,          // bh x 2000 (natural-log units)
    u16* __restrict__ Hend,            // (bh*NC+g) x 128 x 64
    float* __restrict__ cbuf,          // bh*NC+g
    const float* __restrict__ A_log,
    const float* __restrict__ Dskip,
    int eg)
{
    const int g = blockIdx.x, h = blockIdx.y, b = blockIdx.z;
    const int t = threadIdx.x;
    const int ln = t & 63, w = t >> 6;     // 16 waves
    const int rt = w >> 1;                 // S row-tile 0..7
    const int ch = w & 1;                  // column half
    const int bh = b*NH + h;
    const int l0 = g * TCH;

    __shared__ u16 Bc[TCH][LPAD];
    __shared__ u16 Cc[TCH][LPAD];
    __shared__ u16 Xt[HD][LPAD];
    __shared__ u16 Pb[TCH][LPAD];
    __shared__ float ac[TCH], wj[TCH], dtb[TCH];

    const float Ah = -__expf(A_log[eg*NH + h]);
    const float Dv = Dskip[eg*NH + h];

    {   // stage: 8 threads per row (i = t>>3), 16 cols each for B/C, 8 for x
        const int i = t >> 3, q = t & 7;
        const bool v = (l0 + i) < L_SEQ;
        const u16* src = XCONV + (size_t)(b*L_SEQ + l0 + i) * CONVD;
        const short8 z8 = {0,0,0,0,0,0,0,0};
        #pragma unroll
        for (int u = 0; u < 2; ++u) {
            const int col = q*16 + u*8;
            short8 bv = v ? *(const short8*)(src + 1024 + col) : z8;
            short8 cv = v ? *(const short8*)(src + 1152 + col) : z8;
            *(short8*)&Bc[i][col] = bv;
            *(short8*)&Cc[i][col] = cv;
        }
        {
            short8 xv = v ? *(const short8*)(src + h*HD + q*8) : z8;
            #pragma unroll
            for (int k = 0; k < 8; ++k)
                Xt[q*8 + k][i] = ((const u16*)&xv)[k];
        }
        if (t < TCH) {
            const int l = l0 + t;
            dtb[t] = (l < L_SEQ) ? DT[(size_t)(b*L_SEQ + l)*NH + h] : 0.f;
        }
    }
    __syncthreads();

    if (w == 0) {
        float s0 = dtb[ln] * Ah;
        float s1 = dtb[64 + ln] * Ah;
        #pragma unroll
        for (int o = 1; o < 64; o <<= 1) {
            float v0 = __shfl_up(s0, o);
            float v1 = __shfl_up(s1, o);
            if (ln >= o) { s0 += v0; s1 += v1; }
        }
        s1 += __shfl(s0, 63);
        const float acT = __shfl(s1, 63);
        ac[ln] = s0; ac[64 + ln] = s1;
        wj[ln]      = __expf(acT - s0) * dtb[ln];
        wj[64 + ln] = __expf(acT - s1) * dtb[64 + ln];
        if (l0 + ln < L_SEQ)      Acum[(size_t)bh*L_SEQ + l0 + ln] = s0;
        if (l0 + 64 + ln < L_SEQ) Acum[(size_t)bh*L_SEQ + l0 + 64 + ln] = s1;
        if (ln == 63) cbuf[bh*NC + g] = __expf(acT);
    }
    __syncthreads();

    // S = Cc @ Bc^T: wave covers row-tile rt, col-tiles ch*4..ch*4+4
    f32x4 sacc[4];
    #pragma unroll
    for (int c = 0; c < 4; ++c) { sacc[c][0]=0.f; sacc[c][1]=0.f; sacc[c][2]=0.f; sacc[c][3]=0.f; }
    #pragma unroll
    for (int ks = 0; ks < 4; ++ks) {
        short8 afr = *(const short8*)&Cc[rt*16 + (ln & 15)][ks*32 + (ln >> 4)*8];
        #pragma unroll
        for (int c = 0; c < 4; ++c) {
            const int ct = ch*4 + c;
            short8 bfr = *(const short8*)&Bc[ct*16 + (ln & 15)][ks*32 + (ln >> 4)*8];
            sacc[c] = __builtin_amdgcn_mfma_f32_16x16x32_bf16(afr, bfr, sacc[c], 0, 0, 0);
        }
    }
    // P = mask(j<=i) * S * exp(ac_i - ac_j) * dt_j
    {
        const int i0 = rt*16 + (ln >> 4)*4;
        float aci[4];
        #pragma unroll
        for (int r = 0; r < 4; ++r) aci[r] = ac[i0 + r];
        #pragma unroll
        for (int c = 0; c < 4; ++c) {
            const int j = (ch*4 + c)*16 + (ln & 15);
            const float acj = ac[j], dtj = dtb[j];
            #pragma unroll
            for (int r = 0; r < 4; ++r) {
                const int i2 = i0 + r;
                float pv = (j <= i2) ? sacc[c][r] * __expf(aci[r] - acj) * dtj : 0.f;
                Pb[i2][j] = f2bf(pv);
            }
        }
    }
    __syncthreads();

    // Y1 = P @ X (+ D*x): wave covers row-tile rt, pt in {ch*2, ch*2+1}
    {
        f32x4 yacc[2];
        #pragma unroll
        for (int p = 0; p < 2; ++p) { yacc[p][0]=0.f; yacc[p][1]=0.f; yacc[p][2]=0.f; yacc[p][3]=0.f; }
        #pragma unroll
        for (int ks = 0; ks < 4; ++ks) {
            short8 afr = *(const short8*)&Pb[rt*16 + (ln & 15)][ks*32 + (ln >> 4)*8];
            #pragma unroll
            for (int p = 0; p < 2; ++p) {
                const int pt = ch*2 + p;
                short8 bfr = *(const short8*)&Xt[pt*16 + (ln & 15)][ks*32 + (ln >> 4)*8];
                yacc[p] = __builtin_amdgcn_mfma_f32_16x16x32_bf16(afr, bfr, yacc[p], 0, 0, 0);
            }
        }
        #pragma unroll
        for (int p = 0; p < 2; ++p) {
            const int pp = (ch*2 + p)*16 + (ln & 15);
            #pragma unroll
            for (int r = 0; r < 4; ++r) {
                const int i2 = rt*16 + (ln >> 4)*4 + r;
                const int lg = l0 + i2;
                if (lg < L_SEQ) {
                    const float xv = bf2f(Xt[pp][i2]);
                    XCONV[(size_t)(b*L_SEQ + lg)*CONVD + h*HD + pp] =
                        f2bf(yacc[p][r] + Dv * xv);
                }
            }
        }
    }

    // Hloc = (Bc^T * wj) @ X: wave covers n-tile rt, pt in {ch*2, ch*2+1}
    {
        f32x4 hacc[2];
        #pragma unroll
        for (int p = 0; p < 2; ++p) { hacc[p][0]=0.f; hacc[p][1]=0.f; hacc[p][2]=0.f; hacc[p][3]=0.f; }
        #pragma unroll
        for (int ks = 0; ks < 4; ++ks) {
            const int jb = ks*32 + (ln >> 4)*8;
            const int nr = rt*16 + (ln & 15);
            short8 afr;
            #pragma unroll
            for (int jj = 0; jj < 8; ++jj)
                afr[jj] = (short)f2bf(bf2f(Bc[jb + jj][nr]) * wj[jb + jj]);
            #pragma unroll
            for (int p = 0; p < 2; ++p) {
                const int pt = ch*2 + p;
                short8 bfr = *(const short8*)&Xt[pt*16 + (ln & 15)][jb];
                hacc[p] = __builtin_amdgcn_mfma_f32_16x16x32_bf16(afr, bfr, hacc[p], 0, 0, 0);
            }
        }
        u16* Hb = Hend + (size_t)(bh*NC + g) * (TCH*HD);
        #pragma unroll
        for (int p = 0; p < 2; ++p)
            #pragma unroll
            for (int r = 0; r < 4; ++r) {
                const int n = rt*16 + (ln >> 4)*4 + r;
                Hb[n*HD + (ch*2 + p)*16 + (ln & 15)] = f2bf(hacc[p][r]);
            }
    }
}

// --------------------------------------- pass 2: chunk-state propagation ----
__global__ void __launch_bounds__(256) prop_kernel(
    u16* __restrict__ Hend, const float* __restrict__ cbuf)
{
    const int bh = blockIdx.x;
    const int t  = threadIdx.x;
    float hs[32];
    #pragma unroll
    for (int j = 0; j < 32; ++j) hs[j] = 0.f;
    for (int g = 0; g < NC - 1; ++g) {
        const float ce = cbuf[bh*NC + g];
        u16* He = Hend + (size_t)(bh*NC + g)*(TCH*HD) + t*32;
        #pragma unroll
        for (int j = 0; j < 32; ++j) {
            const float lo = bf2f(He[j]);
            hs[j] = ce*hs[j] + lo;
            He[j] = f2bf(hs[j]);
        }
    }
}

// --------------------------------------------- pass 3: Y2 = Cs @ h_start ----
__global__ void __launch_bounds__(256) ssd2_kernel(
    u16* __restrict__ XCONV,
    const float* __restrict__ Acum,    // natural-log units
    const u16* __restrict__ Hend)
{
    const int g = blockIdx.x + 1, h = blockIdx.y, b = blockIdx.z;
    const int t = threadIdx.x, ln = t & 63, w = t >> 6;
    const int bh = b*NH + h;
    const int l0 = g * TCH;

    __shared__ u16 Cs[TCH][LPAD];
    __shared__ u16 Ht[HD][LPAD];

    {
        const int i = t >> 1, q = t & 1;
        const bool v = (l0 + i) < L_SEQ;
        const float eaci = v ? __expf(Acum[(size_t)bh*L_SEQ + l0 + i]) : 0.f;
        const u16* src = XCONV + (size_t)(b*L_SEQ + l0 + i)*CONVD + 1152 + q*64;
        const short8 z8 = {0,0,0,0,0,0,0,0};
        #pragma unroll
        for (int u = 0; u < 8; ++u) {
            short8 cv = v ? *(const short8*)(src + u*8) : z8;
            short8 ov;
            #pragma unroll
            for (int k = 0; k < 8; ++k)
                ov[k] = (short)f2bf(bf2f(((const u16*)&cv)[k]) * eaci);
            *(short8*)&Cs[i][q*64 + u*8] = ov;
        }
    }
    {
        const u16* Hb = Hend + (size_t)(bh*NC + g - 1)*(TCH*HD) + t*32;
        #pragma unroll
        for (int k = 0; k < 32; ++k) {
            const int idx = t*32 + k;
            Ht[idx & 63][idx >> 6] = Hb[k];
        }
    }
    __syncthreads();

    f32x4 acc2[2][4];
    #pragma unroll
    for (int rt = 0; rt < 2; ++rt)
        #pragma unroll
        for (int pt = 0; pt < 4; ++pt) { acc2[rt][pt][0]=0.f; acc2[rt][pt][1]=0.f; acc2[rt][pt][2]=0.f; acc2[rt][pt][3]=0.f; }
    #pragma unroll
    for (int ks = 0; ks < 4; ++ks) {
        short8 af0 = *(const short8*)&Cs[w*32 +      (ln & 15)][ks*32 + (ln >> 4)*8];
        short8 af1 = *(const short8*)&Cs[w*32 + 16 + (ln & 15)][ks*32 + (ln >> 4)*8];
        #pragma unroll
        for (int pt = 0; pt < 4; ++pt) {
            short8 bfr = *(const short8*)&Ht[pt*16 + (ln & 15)][ks*32 + (ln >> 4)*8];
            acc2[0][pt] = __builtin_amdgcn_mfma_f32_16x16x32_bf16(af0, bfr, acc2[0][pt], 0, 0, 0);
            acc2[1][pt] = __builtin_amdgcn_mfma_f32_16x16x32_bf16(af1, bfr, acc2[1][pt], 0, 0, 0);
        }
    }
    #pragma unroll
    for (int rt = 0; rt < 2; ++rt)
        #pragma unroll
        for (int pt = 0; pt < 4; ++pt)
            #pragma unroll
            for (int r = 0; r < 4; ++r) {
                const int i2 = w*32 + rt*16 + (ln >> 4)*4 + r;
                const int lg = l0 + i2;
                if (lg < L_SEQ) {
                    u16* yp = XCONV + (size_t)(b*L_SEQ + lg)*CONVD + h*HD + pt*16 + (ln & 15);
                    *yp = f2bf(bf2f(*yp) + acc2[rt][pt][r]);
                }
            }
}

// ------------------------------------------------- gated RMS norm (bf16) ----
__global__ void __launch_bounds__(256) norm_kernel(
    u16* __restrict__ Ybuf,            // rows, stride 1280 (bf16), in-place
    const u16* __restrict__ Z,         // rows x 1024 bf16
    const float* __restrict__ nw)      // 1024
{
    const int row = blockIdx.x;
    const int t = threadIdx.x;
    u16* y = Ybuf + (size_t)row * CONVD;
    const u16* z = Z + (size_t)row * DINNER;

    ushort4 yv = *(const ushort4*)(y + t*4);
    ushort4 zv = *(const ushort4*)(z + t*4);
    float v[4]; float ss = 0.f;
    #pragma unroll
    for (int j = 0; j < 4; ++j) {
        const float zz = bf2f(((const u16*)&zv)[j]);
        const float vv = bf2f(((const u16*)&yv)[j]) * siluf(zz);
        v[j] = vv; ss += vv*vv;
    }
    #pragma unroll
    for (int o = 32; o > 0; o >>= 1) ss += __shfl_down(ss, o);
    __shared__ float wsum[4];
    if ((t & 63) == 0) wsum[t >> 6] = ss;
    __syncthreads();
    const float total = wsum[0] + wsum[1] + wsum[2] + wsum[3];
    const float scale = rsqrtf(total / (float)DINNER + 1e-5f);
    ushort4 ov;
    #pragma unroll
    for (int j = 0; j < 4; ++j)
        ((u16*)&ov)[j] = f2bf(v[j] * scale * nw[t*4 + j]);
    *(ushort4*)(y + t*4) = ov;
}

// ------------------------------------------------------------------ host ----
extern "C" void kernel_launch(void* const* d_in, const int* in_sizes, int n_in,
                              void* d_out, int out_size, void* d_ws, size_t ws_size,
                              hipStream_t stream)
{
    const float* x        = (const float*)d_in[0];
    const float* gate_w   = (const float*)d_in[1];
    const float* gate_b   = (const float*)d_in[2];
    const float* gate_n   = (const float*)d_in[3];
    const float* in_w     = (const float*)d_in[4];
    const float* conv_w   = (const float*)d_in[5];
    const float* conv_b   = (const float*)d_in[6];
    const float* dt_bias  = (const float*)d_in[7];
    const float* A_log    = (const float*)d_in[8];
    const float* Dskip    = (const float*)d_in[9];
    const float* norm_w   = (const float*)d_in[10];
    const float* out_w    = (const float*)d_in[11];
    float* out = (float*)d_out;

    char* ws = (char*)d_ws;
    // R1 serves sequentially: XBCraw bf16 (gemm->conv) -> Hend (ssd1->ssd2)
    //                         -> Ztile bf16 full-M (z-gemm->norm)
    u16*   R1     = (u16*)ws;                        // 20,480,000 B
    u16*   XCONV  = (u16*)(ws + 20480000);           // 20,480,000 B
    u16*   xbf    = (u16*)(ws + 40960000);           //  8,192,000 B
    u16*   inwb   = (u16*)(ws + 49152000);           //  9,502,720 B (4x2320x512)
    u16*   outwb  = (u16*)(ws + 58654720);           //  4,194,304 B
    float* DTb    = (float*)(ws + 62849024);         //    512,000 B
    float* Acum   = (float*)(ws + 63361024);         //    512,000 B
    float* cbuf   = (float*)(ws + 63873024);         //      4,096 B
    float* maskb  = (float*)(ws + 63877120);         //    128,000 B
    // total 64,005,120 B (< 74.36 MB proven-safe)

    gate_kernel<<<M_TOK, 64, 0, stream>>>(x, gate_w, gate_b, gate_n, maskb);
    // one-time bf16 conversions
    cvt_kernel<<<2000, 256, 0, stream>>>(x, xbf, 512000);
    for (int e = 0; e < NEXP; ++e)
        cvt_kernel<<<580, 256, 0, stream>>>(
            in_w + (size_t)e*DIN_ALL*DMODEL, inwb + (size_t)e*DIN_ALL*512, 148480);
    cvt_kernel<<<1024, 256, 0, stream>>>(out_w, outwb, 262144);

    for (int e = 0; e < NEXP; ++e) {
        const u16* Wxbcdt = inwb + (size_t)e*DIN_ALL*512 + (size_t)1024*512;
        const u16* Wz     = inwb + (size_t)e*DIN_ALL*512;
        // raw xBC (bf16) + dt (f32 softplus) fused
        gemm_bb<4><<<dim3(11, 63), 512, 0, stream>>>(
            xbf, DMODEL, M_TOK, Wxbcdt, DMODEL, 1296,
            R1, CONVD, nullptr, 0, 0, DTb, dt_bias + e*NH);
        conv_kernel<<<5000, 256, 0, stream>>>(R1, XCONV, conv_w, conv_b, e);
        ssd1_kernel<<<dim3(NC, NH, BATCH), 1024, 0, stream>>>(
            XCONV, DTb, Acum, (u16*)R1, cbuf, A_log, Dskip, e);
        prop_kernel<<<BATCH*NH, 256, 0, stream>>>((u16*)R1, cbuf);
        ssd2_kernel<<<dim3(NC - 1, NH, BATCH), 256, 0, stream>>>(
            XCONV, Acum, (const u16*)R1);
        // z (bf16, full M) into R1 (Hend now dead)
        gemm_bb<0><<<dim3(8, 63), 512, 0, stream>>>(
            xbf, DMODEL, M_TOK, Wz, DMODEL, DINNER,
            R1, DINNER, nullptr, 0, 0, nullptr, nullptr);
        norm_kernel<<<M_TOK, 256, 0, stream>>>(
            XCONV, R1, norm_w + (size_t)e*DINNER);
        gemm_bb<2><<<dim3(4, 63), 512, 0, stream>>>(
            XCONV, CONVD, M_TOK, outwb + (size_t)e*DMODEL*DINNER, DINNER, DMODEL,
            out, 512, maskb, e, e == 0 ? 1 : 0, nullptr, nullptr);
    }
}

// Round 18
// 644.116 us; speedup vs baseline: 1.3568x; 1.3176x over previous
//
#include <hip/hip_runtime.h>
#include <hip/hip_bf16.h>

#define M_TOK   8000
#define L_SEQ   2000
#define BATCH   4
#define NEXP    4
#define NH      16
#define HD      64
#define DSTATE  128
#define DMODEL  512
#define DINNER  1024
#define CONVD   1280
#define DIN_ALL 2320   // 1024 z + 1280 xBC + 16 dt
#define TCH     128    // SSD chunk length
#define NC      16     // chunks per sequence
#define LPAD    136    // LDS row pitch (shorts) for SSD tiles

// per-expert element strides (big path)
#define S_XC   10240000u   // XBC/XCONV: 8000*1280 u16
#define S_HE    8388608u   // Hend: 64*16*128*64 u16
#define S_ZT    8192000u   // Ztile: 8000*1024 u16
#define S_DT     128000u   // DT: 8000*16 f32
#define S_AC     128000u   // Acum: 64*2000 f32
#define S_CB       1024u   // cbuf: 64*16 f32
#define S_WI    1187840u   // in_w: 2320*512 u16
#define S_WO     524288u   // out_w: 512*1024 u16

typedef __attribute__((ext_vector_type(8))) short short8;
typedef __attribute__((ext_vector_type(4))) float f32x4;
typedef unsigned short u16;

__device__ __forceinline__ float siluf(float v) {
    return v / (1.f + __expf(-v));
}
__device__ __forceinline__ float softplusf(float v) {
    return v > 20.f ? v : log1pf(expf(v));
}
__device__ __forceinline__ u16 f2bf(float f) {
    union { float f; unsigned u; } x; x.f = f;
    return (u16)((x.u + 0x7fffu + ((x.u >> 16) & 1u)) >> 16);
}
__device__ __forceinline__ float bf2f(u16 v) {
    union { unsigned u; float f; } x; x.u = ((unsigned)v) << 16; return x.f;
}
__device__ __forceinline__ void gl16(const void* g, void* l) {
    __builtin_amdgcn_global_load_lds(
        (const __attribute__((address_space(1))) void*)g,
        (__attribute__((address_space(3))) void*)l, 16, 0, 0);
}

// ---------------------------------------------------------------- gating ----
__global__ void __launch_bounds__(64) gate_kernel(
    const float* __restrict__ X, const float* __restrict__ GW,
    const float* __restrict__ GB, const float* __restrict__ GN,
    float* __restrict__ mask)
{
    const int m = blockIdx.x;
    const int t = threadIdx.x;
    const float* x = X + (size_t)m * DMODEL;
    float s0 = 0.f, s1 = 0.f, s2 = 0.f, s3 = 0.f;
    for (int k = t; k < DMODEL; k += 64) {
        float xv = x[k];
        s0 += xv * GW[k];
        s1 += xv * GW[512 + k];
        s2 += xv * GW[1024 + k];
        s3 += xv * GW[1536 + k];
    }
    #pragma unroll
    for (int o = 32; o > 0; o >>= 1) {
        s0 += __shfl_down(s0, o);
        s1 += __shfl_down(s1, o);
        s2 += __shfl_down(s2, o);
        s3 += __shfl_down(s3, o);
    }
    if (t == 0) {
        float lg[4] = { s0 + GB[0] + GN[m*4+0]*0.01f,
                        s1 + GB[1] + GN[m*4+1]*0.01f,
                        s2 + GB[2] + GN[m*4+2]*0.01f,
                        s3 + GB[3] + GN[m*4+3]*0.01f };
        float mx = fmaxf(fmaxf(lg[0], lg[1]), fmaxf(lg[2], lg[3]));
        float p[4]; float sum = 0.f;
        #pragma unroll
        for (int e = 0; e < 4; ++e) { p[e] = expf(lg[e] - mx); sum += p[e]; }
        #pragma unroll
        for (int e = 0; e < 4; ++e) p[e] /= sum;
        int i0 = 0;
        #pragma unroll
        for (int e = 1; e < 4; ++e) if (p[e] > p[i0]) i0 = e;
        int i1 = -1;
        #pragma unroll
        for (int e = 0; e < 4; ++e) {
            if (e == i0) continue;
            if (i1 < 0 || p[e] > p[i1]) i1 = e;
        }
        float s2v = p[i0] + p[i1];
        #pragma unroll
        for (int e = 0; e < 4; ++e)
            mask[m*4 + e] = (e == i0 || e == i1) ? p[e] / s2v : 0.f;
    }
}

// ------------------------------------------------------- f32 -> bf16 copy ---
__global__ void __launch_bounds__(256) cvt_kernel(
    const float* __restrict__ src, u16* __restrict__ dst, int n8)
{
    const int i = blockIdx.x * 256 + threadIdx.x;
    if (i >= n8) return;
    const float4 a = ((const float4*)src)[i*2];
    const float4 b = ((const float4*)src)[i*2 + 1];
    short8 o;
    o[0]=f2bf(a.x); o[1]=f2bf(a.y); o[2]=f2bf(a.z); o[3]=f2bf(a.w);
    o[4]=f2bf(b.x); o[5]=f2bf(b.y); o[6]=f2bf(b.z); o[7]=f2bf(b.w);
    ((short8*)dst)[i] = o;
}

// --------------------------- bf16 GEMM (8-wave, 2-phase double-buffered) ----
// Expert-batched: ez = blockIdx.z; B/OUT/OUT2/bias offset by per-expert stride.
// MODE 0: OUT bf16 stride ldo. MODE 2: OUT f32 512-stride, (+)= mask*acc,
// mask col = e0+ez. MODE 4: n<1280 bf16; 1280..1296 -> OUT2 softplus(+bias).
template<int MODE>
__global__ void __launch_bounds__(512) gemm_bb(
    const u16* __restrict__ A, int lda, int Mrows,
    const u16* __restrict__ B, int K, int Nrows,
    void* __restrict__ OUT, int ldo,
    const float* __restrict__ mask, int e0, int first,
    float* __restrict__ OUT2, const float* __restrict__ bias,
    size_t strideB, size_t strideO, size_t strideO2)
{
    __shared__ u16 As[2][128][64];
    __shared__ u16 Bs[2][128][64];
    const int t  = threadIdx.x;
    const int ez = blockIdx.z;
    B += (size_t)ez * strideB;
    u16*   OUTu = (u16*)OUT + (size_t)ez * strideO;
    float* OUTf = (float*)OUT + (size_t)ez * strideO;
    if (MODE == 4) { OUT2 += (size_t)ez * strideO2; bias += (size_t)ez * NH; }
    // XCD-aware bijective block swizzle (m204), per z-slice
    const int nbx = gridDim.x;
    const int nwg = nbx * gridDim.y;
    int bid = blockIdx.y * nbx + blockIdx.x;
    {
        const int xcd = bid & 7, lo = bid >> 3;
        const int q8 = nwg >> 3, r8 = nwg & 7;
        bid = (xcd < r8 ? xcd*(q8+1) : r8*(q8+1) + (xcd - r8)*q8) + lo;
    }
    const int m0 = (bid / nbx) * 128;
    const int n0 = (bid % nbx) * 128;
    const int w  = t >> 6, l = t & 63;
    const int wm = (w >> 2) * 64, wn = (w & 3) * 32;
    const int sr = l >> 3;
    const int sc = (l & 7) * 8;

    f32x4 acc[4][2];
    #pragma unroll
    for (int i = 0; i < 4; ++i)
        #pragma unroll
        for (int j = 0; j < 2; ++j) {
            acc[i][j][0]=0.f; acc[i][j][1]=0.f; acc[i][j][2]=0.f; acc[i][j][3]=0.f;
        }

    const int nk = K >> 6;
    #pragma unroll
    for (int c = 0; c < 2; ++c) {
        const int row = c*64 + w*8;
        int ga = m0 + row + sr; if (ga >= Mrows) ga = Mrows - 1;
        gl16(A + (size_t)ga*lda + sc, &As[0][row][0]);
        int gb = n0 + row + sr; if (gb >= Nrows) gb = Nrows - 1;
        gl16(B + (size_t)gb*K + sc, &Bs[0][row][0]);
    }
    __syncthreads();

    for (int kt = 0; kt < nk; ++kt) {
        const int cur = kt & 1;
        if (kt + 1 < nk) {
            const int nxt = cur ^ 1;
            const int k0 = (kt + 1) << 6;
            #pragma unroll
            for (int c = 0; c < 2; ++c) {
                const int row = c*64 + w*8;
                int ga = m0 + row + sr; if (ga >= Mrows) ga = Mrows - 1;
                gl16(A + (size_t)ga*lda + k0 + sc, &As[nxt][row][0]);
                int gb = n0 + row + sr; if (gb >= Nrows) gb = Nrows - 1;
                gl16(B + (size_t)gb*K + k0 + sc, &Bs[nxt][row][0]);
            }
        }
        #pragma unroll
        for (int ks = 0; ks < 2; ++ks) {
            short8 af[4], bf[2];
            const int ko = ks*32 + (l >> 4)*8;
            #pragma unroll
            for (int i = 0; i < 4; ++i)
                af[i] = *(const short8*)&As[cur][wm + i*16 + (l & 15)][ko];
            #pragma unroll
            for (int j = 0; j < 2; ++j)
                bf[j] = *(const short8*)&Bs[cur][wn + j*16 + (l & 15)][ko];
            #pragma unroll
            for (int i = 0; i < 4; ++i)
                #pragma unroll
                for (int j = 0; j < 2; ++j)
                    acc[i][j] = __builtin_amdgcn_mfma_f32_16x16x32_bf16(
                        af[i], bf[j], acc[i][j], 0, 0, 0);
        }
        __syncthreads();
    }

    #pragma unroll
    for (int i = 0; i < 4; ++i) {
        #pragma unroll
        for (int r = 0; r < 4; ++r) {
            const int m = m0 + wm + i*16 + (l >> 4)*4 + r;
            if (m >= Mrows) continue;
            if (MODE == 2) {
                const float wgt = mask[m*4 + e0 + ez];
                #pragma unroll
                for (int j = 0; j < 2; ++j) {
                    const int n = n0 + wn + j*16 + (l & 15);
                    float* o = OUTf + (size_t)m*512 + n;
                    const float v = wgt * acc[i][j][r];
                    *o = first ? v : *o + v;
                }
            } else if (MODE == 4) {
                #pragma unroll
                for (int j = 0; j < 2; ++j) {
                    const int n = n0 + wn + j*16 + (l & 15);
                    if (n < CONVD) {
                        OUTu[(size_t)m*ldo + n] = f2bf(acc[i][j][r]);
                    } else if (n < CONVD + NH) {
                        OUT2[(size_t)m*NH + (n - CONVD)] =
                            softplusf(acc[i][j][r] + bias[n - CONVD]);
                    }
                }
            } else {
                #pragma unroll
                for (int j = 0; j < 2; ++j) {
                    const int n = n0 + wn + j*16 + (l & 15);
                    OUTu[(size_t)m*ldo + n] = f2bf(acc[i][j][r]);
                }
            }
        }
    }
}

// ---------------------------------------- conv4 + SiLU, direct (no LDS) -----
// Expert via blockIdx.y.
__global__ void __launch_bounds__(256) conv_kernel(
    const u16* __restrict__ XBC,     // (ne) x M x 1280 bf16 raw
    u16* __restrict__ XCONV,         // (ne) x M x 1280 bf16
    const float* __restrict__ conv_w,
    const float* __restrict__ conv_b,
    int e0)
{
    const int e = blockIdx.y;
    XBC   += (size_t)e * S_XC;
    XCONV += (size_t)e * S_XC;
    const int eg = e0 + e;
    const int idx = blockIdx.x * 256 + threadIdx.x;
    const int NCG = CONVD / 8;                  // 160
    if (idx >= M_TOK * NCG) return;
    const int cg = idx % NCG;
    const int m  = idx / NCG;
    const int b  = m / L_SEQ, l = m - b*L_SEQ;
    const int c0 = cg * 8;

    const u16* base = XBC + (size_t)b*L_SEQ*CONVD + c0;
    const short8 z8 = {0,0,0,0,0,0,0,0};
    short8 r[4];
    #pragma unroll
    for (int k = 0; k < 4; ++k) {
        const int row = l - 3 + k;
        r[k] = (row >= 0) ? *(const short8*)(base + (size_t)row*CONVD) : z8;
    }
    const float4* wp = (const float4*)(conv_w + ((size_t)eg*CONVD + c0)*4);
    const float*  bp = conv_b + (size_t)eg*CONVD + c0;
    short8 o;
    #pragma unroll
    for (int j = 0; j < 8; ++j) {
        const float4 wj = wp[j];
        float v = bf2f(r[0][j])*wj.x + bf2f(r[1][j])*wj.y
                + bf2f(r[2][j])*wj.z + bf2f(r[3][j])*wj.w + bp[j];
        o[j] = f2bf(siluf(v));
    }
    *(short8*)(XCONV + (size_t)m*CONVD + c0) = o;
}

// --------------------------------------------------- SSD pass 1 (per chunk) -
// 1024 threads / 16 waves. Expert from blockIdx.z: e = z>>2, b = z&3.
__global__ void __launch_bounds__(1024) ssd1_kernel(
    u16* __restrict__ XCONV,
    const float* __restrict__ DT,
    float* __restrict__ Acum,
    u16* __restrict__ Hend,
    float* __restrict__ cbuf,
    const float* __restrict__ A_log,
    const float* __restrict__ Dskip,
    int e0)
{
    const int g = blockIdx.x, h = blockIdx.y;
    const int bz = blockIdx.z;
    const int e = bz >> 2, b = bz & 3;
    XCONV += (size_t)e * S_XC;
    DT    += (size_t)e * S_DT;
    Acum  += (size_t)e * S_AC;
    Hend  += (size_t)e * S_HE;
    cbuf  += (size_t)e * S_CB;
    const int eg = e0 + e;
    const int t = threadIdx.x;
    const int ln = t & 63, w = t >> 6;
    const int rt = w >> 1;
    const int ch = w & 1;
    const int bh = b*NH + h;
    const int l0 = g * TCH;

    __shared__ u16 Bc[TCH][LPAD];
    __shared__ u16 Cc[TCH][LPAD];
    __shared__ u16 Xt[HD][LPAD];
    __shared__ u16 Pb[TCH][LPAD];
    __shared__ float ac[TCH], wj[TCH], dtb[TCH];

    const float Ah = -__expf(A_log[eg*NH + h]);
    const float Dv = Dskip[eg*NH + h];

    {
        const int i = t >> 3, q = t & 7;
        const bool v = (l0 + i) < L_SEQ;
        const u16* src = XCONV + (size_t)(b*L_SEQ + l0 + i) * CONVD;
        const short8 z8 = {0,0,0,0,0,0,0,0};
        #pragma unroll
        for (int u = 0; u < 2; ++u) {
            const int col = q*16 + u*8;
            short8 bv = v ? *(const short8*)(src + 1024 + col) : z8;
            short8 cv = v ? *(const short8*)(src + 1152 + col) : z8;
            *(short8*)&Bc[i][col] = bv;
            *(short8*)&Cc[i][col] = cv;
        }
        {
            short8 xv = v ? *(const short8*)(src + h*HD + q*8) : z8;
            #pragma unroll
            for (int k = 0; k < 8; ++k)
                Xt[q*8 + k][i] = ((const u16*)&xv)[k];
        }
        if (t < TCH) {
            const int l = l0 + t;
            dtb[t] = (l < L_SEQ) ? DT[(size_t)(b*L_SEQ + l)*NH + h] : 0.f;
        }
    }
    __syncthreads();

    if (w == 0) {
        float s0 = dtb[ln] * Ah;
        float s1 = dtb[64 + ln] * Ah;
        #pragma unroll
        for (int o = 1; o < 64; o <<= 1) {
            float v0 = __shfl_up(s0, o);
            float v1 = __shfl_up(s1, o);
            if (ln >= o) { s0 += v0; s1 += v1; }
        }
        s1 += __shfl(s0, 63);
        const float acT = __shfl(s1, 63);
        ac[ln] = s0; ac[64 + ln] = s1;
        wj[ln]      = __expf(acT - s0) * dtb[ln];
        wj[64 + ln] = __expf(acT - s1) * dtb[64 + ln];
        if (l0 + ln < L_SEQ)      Acum[(size_t)bh*L_SEQ + l0 + ln] = s0;
        if (l0 + 64 + ln < L_SEQ) Acum[(size_t)bh*L_SEQ + l0 + 64 + ln] = s1;
        if (ln == 63) cbuf[bh*NC + g] = __expf(acT);
    }
    __syncthreads();

    f32x4 sacc[4];
    #pragma unroll
    for (int c = 0; c < 4; ++c) { sacc[c][0]=0.f; sacc[c][1]=0.f; sacc[c][2]=0.f; sacc[c][3]=0.f; }
    #pragma unroll
    for (int ks = 0; ks < 4; ++ks) {
        short8 afr = *(const short8*)&Cc[rt*16 + (ln & 15)][ks*32 + (ln >> 4)*8];
        #pragma unroll
        for (int c = 0; c < 4; ++c) {
            const int ct = ch*4 + c;
            short8 bfr = *(const short8*)&Bc[ct*16 + (ln & 15)][ks*32 + (ln >> 4)*8];
            sacc[c] = __builtin_amdgcn_mfma_f32_16x16x32_bf16(afr, bfr, sacc[c], 0, 0, 0);
        }
    }
    {
        const int i0 = rt*16 + (ln >> 4)*4;
        float aci[4];
        #pragma unroll
        for (int r = 0; r < 4; ++r) aci[r] = ac[i0 + r];
        #pragma unroll
        for (int c = 0; c < 4; ++c) {
            const int j = (ch*4 + c)*16 + (ln & 15);
            const float acj = ac[j], dtj = dtb[j];
            #pragma unroll
            for (int r = 0; r < 4; ++r) {
                const int i2 = i0 + r;
                float pv = (j <= i2) ? sacc[c][r] * __expf(aci[r] - acj) * dtj : 0.f;
                Pb[i2][j] = f2bf(pv);
            }
        }
    }
    __syncthreads();

    {
        f32x4 yacc[2];
        #pragma unroll
        for (int p = 0; p < 2; ++p) { yacc[p][0]=0.f; yacc[p][1]=0.f; yacc[p][2]=0.f; yacc[p][3]=0.f; }
        #pragma unroll
        for (int ks = 0; ks < 4; ++ks) {
            short8 afr = *(const short8*)&Pb[rt*16 + (ln & 15)][ks*32 + (ln >> 4)*8];
            #pragma unroll
            for (int p = 0; p < 2; ++p) {
                const int pt = ch*2 + p;
                short8 bfr = *(const short8*)&Xt[pt*16 + (ln & 15)][ks*32 + (ln >> 4)*8];
                yacc[p] = __builtin_amdgcn_mfma_f32_16x16x32_bf16(afr, bfr, yacc[p], 0, 0, 0);
            }
        }
        #pragma unroll
        for (int p = 0; p < 2; ++p) {
            const int pp = (ch*2 + p)*16 + (ln & 15);
            #pragma unroll
            for (int r = 0; r < 4; ++r) {
                const int i2 = rt*16 + (ln >> 4)*4 + r;
                const int lg = l0 + i2;
                if (lg < L_SEQ) {
                    const float xv = bf2f(Xt[pp][i2]);
                    XCONV[(size_t)(b*L_SEQ + lg)*CONVD + h*HD + pp] =
                        f2bf(yacc[p][r] + Dv * xv);
                }
            }
        }
    }

    {
        f32x4 hacc[2];
        #pragma unroll
        for (int p = 0; p < 2; ++p) { hacc[p][0]=0.f; hacc[p][1]=0.f; hacc[p][2]=0.f; hacc[p][3]=0.f; }
        #pragma unroll
        for (int ks = 0; ks < 4; ++ks) {
            const int jb = ks*32 + (ln >> 4)*8;
            const int nr = rt*16 + (ln & 15);
            short8 afr;
            #pragma unroll
            for (int jj = 0; jj < 8; ++jj)
                afr[jj] = (short)f2bf(bf2f(Bc[jb + jj][nr]) * wj[jb + jj]);
            #pragma unroll
            for (int p = 0; p < 2; ++p) {
                const int pt = ch*2 + p;
                short8 bfr = *(const short8*)&Xt[pt*16 + (ln & 15)][jb];
                hacc[p] = __builtin_amdgcn_mfma_f32_16x16x32_bf16(afr, bfr, hacc[p], 0, 0, 0);
            }
        }
        u16* Hb = Hend + (size_t)(bh*NC + g) * (TCH*HD);
        #pragma unroll
        for (int p = 0; p < 2; ++p)
            #pragma unroll
            for (int r = 0; r < 4; ++r) {
                const int n = rt*16 + (ln >> 4)*4 + r;
                Hb[n*HD + (ch*2 + p)*16 + (ln & 15)] = f2bf(hacc[p][r]);
            }
    }
}

// --------------------------------------- pass 2: chunk-state propagation ----
__global__ void __launch_bounds__(256) prop_kernel(
    u16* __restrict__ Hend, const float* __restrict__ cbuf)
{
    const int e  = blockIdx.x >> 6;
    const int bh = blockIdx.x & 63;
    Hend += (size_t)e * S_HE;
    cbuf += (size_t)e * S_CB;
    const int t  = threadIdx.x;
    float hs[32];
    #pragma unroll
    for (int j = 0; j < 32; ++j) hs[j] = 0.f;
    for (int g = 0; g < NC - 1; ++g) {
        const float ce = cbuf[bh*NC + g];
        u16* He = Hend + (size_t)(bh*NC + g)*(TCH*HD) + t*32;
        #pragma unroll
        for (int j = 0; j < 32; ++j) {
            const float lo = bf2f(He[j]);
            hs[j] = ce*hs[j] + lo;
            He[j] = f2bf(hs[j]);
        }
    }
}

// --------------------------------------------- pass 3: Y2 = Cs @ h_start ----
__global__ void __launch_bounds__(256) ssd2_kernel(
    u16* __restrict__ XCONV,
    const float* __restrict__ Acum,
    const u16* __restrict__ Hend)
{
    const int g = blockIdx.x + 1, h = blockIdx.y;
    const int bz = blockIdx.z;
    const int e = bz >> 2, b = bz & 3;
    XCONV += (size_t)e * S_XC;
    Acum  += (size_t)e * S_AC;
    Hend  += (size_t)e * S_HE;
    const int t = threadIdx.x, ln = t & 63, w = t >> 6;
    const int bh = b*NH + h;
    const int l0 = g * TCH;

    __shared__ u16 Cs[TCH][LPAD];
    __shared__ u16 Ht[HD][LPAD];

    {
        const int i = t >> 1, q = t & 1;
        const bool v = (l0 + i) < L_SEQ;
        const float eaci = v ? __expf(Acum[(size_t)bh*L_SEQ + l0 + i]) : 0.f;
        const u16* src = XCONV + (size_t)(b*L_SEQ + l0 + i)*CONVD + 1152 + q*64;
        const short8 z8 = {0,0,0,0,0,0,0,0};
        #pragma unroll
        for (int u = 0; u < 8; ++u) {
            short8 cv = v ? *(const short8*)(src + u*8) : z8;
            short8 ov;
            #pragma unroll
            for (int k = 0; k < 8; ++k)
                ov[k] = (short)f2bf(bf2f(((const u16*)&cv)[k]) * eaci);
            *(short8*)&Cs[i][q*64 + u*8] = ov;
        }
    }
    {
        const u16* Hb = Hend + (size_t)(bh*NC + g - 1)*(TCH*HD) + t*32;
        #pragma unroll
        for (int k = 0; k < 32; ++k) {
            const int idx = t*32 + k;
            Ht[idx & 63][idx >> 6] = Hb[k];
        }
    }
    __syncthreads();

    f32x4 acc2[2][4];
    #pragma unroll
    for (int rt = 0; rt < 2; ++rt)
        #pragma unroll
        for (int pt = 0; pt < 4; ++pt) { acc2[rt][pt][0]=0.f; acc2[rt][pt][1]=0.f; acc2[rt][pt][2]=0.f; acc2[rt][pt][3]=0.f; }
    #pragma unroll
    for (int ks = 0; ks < 4; ++ks) {
        short8 af0 = *(const short8*)&Cs[w*32 +      (ln & 15)][ks*32 + (ln >> 4)*8];
        short8 af1 = *(const short8*)&Cs[w*32 + 16 + (ln & 15)][ks*32 + (ln >> 4)*8];
        #pragma unroll
        for (int pt = 0; pt < 4; ++pt) {
            short8 bfr = *(const short8*)&Ht[pt*16 + (ln & 15)][ks*32 + (ln >> 4)*8];
            acc2[0][pt] = __builtin_amdgcn_mfma_f32_16x16x32_bf16(af0, bfr, acc2[0][pt], 0, 0, 0);
            acc2[1][pt] = __builtin_amdgcn_mfma_f32_16x16x32_bf16(af1, bfr, acc2[1][pt], 0, 0, 0);
        }
    }
    #pragma unroll
    for (int rt = 0; rt < 2; ++rt)
        #pragma unroll
        for (int pt = 0; pt < 4; ++pt)
            #pragma unroll
            for (int r = 0; r < 4; ++r) {
                const int i2 = w*32 + rt*16 + (ln >> 4)*4 + r;
                const int lg = l0 + i2;
                if (lg < L_SEQ) {
                    u16* yp = XCONV + (size_t)(b*L_SEQ + lg)*CONVD + h*HD + pt*16 + (ln & 15);
                    *yp = f2bf(bf2f(*yp) + acc2[rt][pt][r]);
                }
            }
}

// ------------------------------------------------- gated RMS norm (bf16) ----
// Expert via blockIdx.y.
__global__ void __launch_bounds__(256) norm_kernel(
    u16* __restrict__ Ybuf,
    const u16* __restrict__ Z,
    const float* __restrict__ norm_w,
    int e0)
{
    const int e = blockIdx.y;
    Ybuf += (size_t)e * S_XC;
    Z    += (size_t)e * S_ZT;
    const float* nw = norm_w + (size_t)(e0 + e) * DINNER;
    const int row = blockIdx.x;
    const int t = threadIdx.x;
    u16* y = Ybuf + (size_t)row * CONVD;
    const u16* z = Z + (size_t)row * DINNER;

    ushort4 yv = *(const ushort4*)(y + t*4);
    ushort4 zv = *(const ushort4*)(z + t*4);
    float v[4]; float ss = 0.f;
    #pragma unroll
    for (int j = 0; j < 4; ++j) {
        const float zz = bf2f(((const u16*)&zv)[j]);
        const float vv = bf2f(((const u16*)&yv)[j]) * siluf(zz);
        v[j] = vv; ss += vv*vv;
    }
    #pragma unroll
    for (int o = 32; o > 0; o >>= 1) ss += __shfl_down(ss, o);
    __shared__ float wsum[4];
    if ((t & 63) == 0) wsum[t >> 6] = ss;
    __syncthreads();
    const float total = wsum[0] + wsum[1] + wsum[2] + wsum[3];
    const float scale = rsqrtf(total / (float)DINNER + 1e-5f);
    ushort4 ov;
    #pragma unroll
    for (int j = 0; j < 4; ++j)
        ((u16*)&ov)[j] = f2bf(v[j] * scale * nw[t*4 + j]);
    *(ushort4*)(y + t*4) = ov;
}

// ------------------------------------------------------------------ host ----
extern "C" void kernel_launch(void* const* d_in, const int* in_sizes, int n_in,
                              void* d_out, int out_size, void* d_ws, size_t ws_size,
                              hipStream_t stream)
{
    const float* x        = (const float*)d_in[0];
    const float* gate_w   = (const float*)d_in[1];
    const float* gate_b   = (const float*)d_in[2];
    const float* gate_n   = (const float*)d_in[3];
    const float* in_w     = (const float*)d_in[4];
    const float* conv_w   = (const float*)d_in[5];
    const float* conv_b   = (const float*)d_in[6];
    const float* dt_bias  = (const float*)d_in[7];
    const float* A_log    = (const float*)d_in[8];
    const float* Dskip    = (const float*)d_in[9];
    const float* norm_w   = (const float*)d_in[10];
    const float* out_w    = (const float*)d_in[11];
    float* out = (float*)d_out;

    char* ws = (char*)d_ws;
    const size_t NEED_BIG = 189969408;   // all-expert layout
    const bool big = ws_size >= NEED_BIG;

    if (big) {
        // R1 serves sequentially per stage across ALL experts:
        // XBCraw_all (82MB) -> Hend_all (67MB) -> Ztile_all (65.5MB)
        u16*   R1     = (u16*)ws;                        //  81,920,000 B
        u16*   XCONV  = (u16*)(ws + 81920000);           //  81,920,000 B
        u16*   xbf    = (u16*)(ws + 163840000);          //   8,192,000 B
        u16*   inwb   = (u16*)(ws + 172032000);          //   9,502,720 B
        u16*   outwb  = (u16*)(ws + 181534720);          //   4,194,304 B
        float* DTb    = (float*)(ws + 185729024);        //   2,048,000 B
        float* Acum   = (float*)(ws + 187777024);        //   2,048,000 B
        float* cbuf   = (float*)(ws + 189825024);        //      16,384 B
        float* maskb  = (float*)(ws + 189841408);        //     128,000 B

        gate_kernel<<<M_TOK, 64, 0, stream>>>(x, gate_w, gate_b, gate_n, maskb);
        cvt_kernel<<<2000, 256, 0, stream>>>(x, xbf, 512000);
        cvt_kernel<<<2320, 256, 0, stream>>>(in_w, inwb, 593920);
        cvt_kernel<<<1024, 256, 0, stream>>>(out_w, outwb, 262144);

        // xBC + dt, all experts
        gemm_bb<4><<<dim3(11, 63, NEXP), 512, 0, stream>>>(
            xbf, DMODEL, M_TOK, inwb + (size_t)1024*512, DMODEL, 1296,
            R1, CONVD, nullptr, 0, 0, DTb, dt_bias, S_WI, S_XC, S_DT);
        conv_kernel<<<dim3(5000, NEXP), 256, 0, stream>>>(
            R1, XCONV, conv_w, conv_b, 0);
        ssd1_kernel<<<dim3(NC, NH, BATCH*NEXP), 1024, 0, stream>>>(
            XCONV, DTb, Acum, (u16*)R1, cbuf, A_log, Dskip, 0);
        prop_kernel<<<64*NEXP, 256, 0, stream>>>((u16*)R1, cbuf);
        ssd2_kernel<<<dim3(NC - 1, NH, BATCH*NEXP), 256, 0, stream>>>(
            XCONV, Acum, (const u16*)R1);
        // z, all experts (Hend dead)
        gemm_bb<0><<<dim3(8, 63, NEXP), 512, 0, stream>>>(
            xbf, DMODEL, M_TOK, inwb, DMODEL, DINNER,
            R1, DINNER, nullptr, 0, 0, nullptr, nullptr, S_WI, S_ZT, 0);
        norm_kernel<<<dim3(M_TOK, NEXP), 256, 0, stream>>>(
            XCONV, R1, norm_w, 0);
        // out_proj: ordered accumulation, per expert
        for (int e = 0; e < NEXP; ++e)
            gemm_bb<2><<<dim3(4, 63, 1), 512, 0, stream>>>(
                XCONV + (size_t)e*S_XC, CONVD, M_TOK,
                outwb + (size_t)e*S_WO, DINNER, DMODEL,
                out, 512, maskb, e, e == 0 ? 1 : 0, nullptr, nullptr,
                0, 0, 0);
    } else {
        // fallback: per-expert loop in the 64MB layout (round-17 proven)
        u16*   R1     = (u16*)ws;
        u16*   XCONV  = (u16*)(ws + 20480000);
        u16*   xbf    = (u16*)(ws + 40960000);
        u16*   inwb   = (u16*)(ws + 49152000);
        u16*   outwb  = (u16*)(ws + 58654720);
        float* DTb    = (float*)(ws + 62849024);
        float* Acum   = (float*)(ws + 63361024);
        float* cbuf   = (float*)(ws + 63873024);
        float* maskb  = (float*)(ws + 63877120);

        gate_kernel<<<M_TOK, 64, 0, stream>>>(x, gate_w, gate_b, gate_n, maskb);
        cvt_kernel<<<2000, 256, 0, stream>>>(x, xbf, 512000);
        cvt_kernel<<<2320, 256, 0, stream>>>(in_w, inwb, 593920);
        cvt_kernel<<<1024, 256, 0, stream>>>(out_w, outwb, 262144);

        for (int e = 0; e < NEXP; ++e) {
            gemm_bb<4><<<dim3(11, 63, 1), 512, 0, stream>>>(
                xbf, DMODEL, M_TOK,
                inwb + (size_t)e*S_WI + (size_t)1024*512, DMODEL, 1296,
                R1, CONVD, nullptr, 0, 0, DTb, dt_bias + e*NH, 0, 0, 0);
            conv_kernel<<<dim3(5000, 1), 256, 0, stream>>>(
                R1, XCONV, conv_w, conv_b, e);
            ssd1_kernel<<<dim3(NC, NH, BATCH), 1024, 0, stream>>>(
                XCONV, DTb, Acum, (u16*)R1, cbuf, A_log, Dskip, e);
            prop_kernel<<<64, 256, 0, stream>>>((u16*)R1, cbuf);
            ssd2_kernel<<<dim3(NC - 1, NH, BATCH), 256, 0, stream>>>(
                XCONV, Acum, (const u16*)R1);
            gemm_bb<0><<<dim3(8, 63, 1), 512, 0, stream>>>(
                xbf, DMODEL, M_TOK, inwb + (size_t)e*S_WI, DMODEL, DINNER,
                R1, DINNER, nullptr, 0, 0, nullptr, nullptr, 0, 0, 0);
            norm_kernel<<<dim3(M_TOK, 1), 256, 0, stream>>>(
                XCONV, R1, norm_w, e);
            gemm_bb<2><<<dim3(4, 63, 1), 512, 0, stream>>>(
                XCONV, CONVD, M_TOK, outwb + (size_t)e*S_WO, DINNER, DMODEL,
                out, 512, maskb, e, e == 0 ? 1 : 0, nullptr, nullptr, 0, 0, 0);
        }
    }
}

// Round 21
// 605.825 us; speedup vs baseline: 1.4425x; 1.0632x over previous
//
#include <hip/hip_runtime.h>
#include <hip/hip_bf16.h>

#define M_TOK   8000
#define L_SEQ   2000
#define BATCH   4
#define NEXP    4
#define NH      16
#define HD      64
#define DSTATE  128
#define DMODEL  512
#define DINNER  1024
#define CONVD   1280
#define DIN_ALL 2320
#define TCH     128
#define NC      16
#define LPAD    136

// per-expert element strides (big path)
#define S_XC   10240000u
#define S_HE    8388608u
#define S_ZT    8192000u
#define S_DT     128000u
#define S_AC     128000u
#define S_CB       1024u
#define S_WI    1187840u
#define S_WO     524288u
#define S_EO    4096000u   // EO: 8000*512 f32

typedef __attribute__((ext_vector_type(8))) short short8;
typedef __attribute__((ext_vector_type(4))) float f32x4;
typedef unsigned short u16;

__device__ __forceinline__ float siluf(float v) {
    return v / (1.f + __expf(-v));
}
__device__ __forceinline__ float softplusf(float v) {
    return v > 20.f ? v : log1pf(expf(v));
}
__device__ __forceinline__ u16 f2bf(float f) {
    union { float f; unsigned u; } x; x.f = f;
    return (u16)((x.u + 0x7fffu + ((x.u >> 16) & 1u)) >> 16);
}
__device__ __forceinline__ float bf2f(u16 v) {
    union { unsigned u; float f; } x; x.u = ((unsigned)v) << 16; return x.f;
}
__device__ __forceinline__ void gl16(const void* g, void* l) {
    __builtin_amdgcn_global_load_lds(
        (const __attribute__((address_space(1))) void*)g,
        (__attribute__((address_space(3))) void*)l, 16, 0, 0);
}

// ---------------------------------------------------------------- gating ----
__global__ void __launch_bounds__(64) gate_kernel(
    const float* __restrict__ X, const float* __restrict__ GW,
    const float* __restrict__ GB, const float* __restrict__ GN,
    float* __restrict__ mask)
{
    const int m = blockIdx.x;
    const int t = threadIdx.x;
    const float* x = X + (size_t)m * DMODEL;
    float s0 = 0.f, s1 = 0.f, s2 = 0.f, s3 = 0.f;
    for (int k = t; k < DMODEL; k += 64) {
        float xv = x[k];
        s0 += xv * GW[k];
        s1 += xv * GW[512 + k];
        s2 += xv * GW[1024 + k];
        s3 += xv * GW[1536 + k];
    }
    #pragma unroll
    for (int o = 32; o > 0; o >>= 1) {
        s0 += __shfl_down(s0, o);
        s1 += __shfl_down(s1, o);
        s2 += __shfl_down(s2, o);
        s3 += __shfl_down(s3, o);
    }
    if (t == 0) {
        float lg[4] = { s0 + GB[0] + GN[m*4+0]*0.01f,
                        s1 + GB[1] + GN[m*4+1]*0.01f,
                        s2 + GB[2] + GN[m*4+2]*0.01f,
                        s3 + GB[3] + GN[m*4+3]*0.01f };
        float mx = fmaxf(fmaxf(lg[0], lg[1]), fmaxf(lg[2], lg[3]));
        float p[4]; float sum = 0.f;
        #pragma unroll
        for (int e = 0; e < 4; ++e) { p[e] = expf(lg[e] - mx); sum += p[e]; }
        #pragma unroll
        for (int e = 0; e < 4; ++e) p[e] /= sum;
        int i0 = 0;
        #pragma unroll
        for (int e = 1; e < 4; ++e) if (p[e] > p[i0]) i0 = e;
        int i1 = -1;
        #pragma unroll
        for (int e = 0; e < 4; ++e) {
            if (e == i0) continue;
            if (i1 < 0 || p[e] > p[i1]) i1 = e;
        }
        float s2v = p[i0] + p[i1];
        #pragma unroll
        for (int e = 0; e < 4; ++e)
            mask[m*4 + e] = (e == i0 || e == i1) ? p[e] / s2v : 0.f;
    }
}

// ------------------------------------------------------- f32 -> bf16 copy ---
__global__ void __launch_bounds__(256) cvt_kernel(
    const float* __restrict__ src, u16* __restrict__ dst, int n8)
{
    const int i = blockIdx.x * 256 + threadIdx.x;
    if (i >= n8) return;
    const float4 a = ((const float4*)src)[i*2];
    const float4 b = ((const float4*)src)[i*2 + 1];
    short8 o;
    o[0]=f2bf(a.x); o[1]=f2bf(a.y); o[2]=f2bf(a.z); o[3]=f2bf(a.w);
    o[4]=f2bf(b.x); o[5]=f2bf(b.y); o[6]=f2bf(b.z); o[7]=f2bf(b.w);
    ((short8*)dst)[i] = o;
}

// --------------------------- bf16 GEMM (8-wave, 2-phase double-buffered) ----
// Expert-batched: ez = blockIdx.z; A/B/OUT/OUT2/bias offset by per-expert
// strides (strideA for A — out_proj needs per-expert y!).
// MODE 0: bf16 stride ldo. MODE 2: f32 512-stride (+)= mask*acc.
// MODE 4: xBC bf16 + dt softplus. MODE 5: f32 plain acc, stride 512 (EO).
template<int MODE>
__global__ void __launch_bounds__(512) gemm_bb(
    const u16* __restrict__ A, int lda, int Mrows,
    const u16* __restrict__ B, int K, int Nrows,
    void* __restrict__ OUT, int ldo,
    const float* __restrict__ mask, int e0, int first,
    float* __restrict__ OUT2, const float* __restrict__ bias,
    size_t strideA, size_t strideB, size_t strideO, size_t strideO2)
{
    __shared__ u16 As[2][128][64];
    __shared__ u16 Bs[2][128][64];
    const int t  = threadIdx.x;
    const int ez = blockIdx.z;
    A += (size_t)ez * strideA;
    B += (size_t)ez * strideB;
    u16*   OUTu = (u16*)OUT + (size_t)ez * strideO;
    float* OUTf = (float*)OUT + (size_t)ez * strideO;
    if (MODE == 4) { OUT2 += (size_t)ez * strideO2; bias += (size_t)ez * NH; }
    const int nbx = gridDim.x;
    const int nwg = nbx * gridDim.y;
    int bid = blockIdx.y * nbx + blockIdx.x;
    {
        const int xcd = bid & 7, lo = bid >> 3;
        const int q8 = nwg >> 3, r8 = nwg & 7;
        bid = (xcd < r8 ? xcd*(q8+1) : r8*(q8+1) + (xcd - r8)*q8) + lo;
    }
    const int m0 = (bid / nbx) * 128;
    const int n0 = (bid % nbx) * 128;
    const int w  = t >> 6, l = t & 63;
    const int wm = (w >> 2) * 64, wn = (w & 3) * 32;
    const int sr = l >> 3;
    const int sc = (l & 7) * 8;

    f32x4 acc[4][2];
    #pragma unroll
    for (int i = 0; i < 4; ++i)
        #pragma unroll
        for (int j = 0; j < 2; ++j) {
            acc[i][j][0]=0.f; acc[i][j][1]=0.f; acc[i][j][2]=0.f; acc[i][j][3]=0.f;
        }

    const int nk = K >> 6;
    #pragma unroll
    for (int c = 0; c < 2; ++c) {
        const int row = c*64 + w*8;
        int ga = m0 + row + sr; if (ga >= Mrows) ga = Mrows - 1;
        gl16(A + (size_t)ga*lda + sc, &As[0][row][0]);
        int gb = n0 + row + sr; if (gb >= Nrows) gb = Nrows - 1;
        gl16(B + (size_t)gb*K + sc, &Bs[0][row][0]);
    }
    __syncthreads();

    for (int kt = 0; kt < nk; ++kt) {
        const int cur = kt & 1;
        if (kt + 1 < nk) {
            const int nxt = cur ^ 1;
            const int k0 = (kt + 1) << 6;
            #pragma unroll
            for (int c = 0; c < 2; ++c) {
                const int row = c*64 + w*8;
                int ga = m0 + row + sr; if (ga >= Mrows) ga = Mrows - 1;
                gl16(A + (size_t)ga*lda + k0 + sc, &As[nxt][row][0]);
                int gb = n0 + row + sr; if (gb >= Nrows) gb = Nrows - 1;
                gl16(B + (size_t)gb*K + k0 + sc, &Bs[nxt][row][0]);
            }
        }
        #pragma unroll
        for (int ks = 0; ks < 2; ++ks) {
            short8 af[4], bf[2];
            const int ko = ks*32 + (l >> 4)*8;
            #pragma unroll
            for (int i = 0; i < 4; ++i)
                af[i] = *(const short8*)&As[cur][wm + i*16 + (l & 15)][ko];
            #pragma unroll
            for (int j = 0; j < 2; ++j)
                bf[j] = *(const short8*)&Bs[cur][wn + j*16 + (l & 15)][ko];
            #pragma unroll
            for (int i = 0; i < 4; ++i)
                #pragma unroll
                for (int j = 0; j < 2; ++j)
                    acc[i][j] = __builtin_amdgcn_mfma_f32_16x16x32_bf16(
                        af[i], bf[j], acc[i][j], 0, 0, 0);
        }
        __syncthreads();
    }

    #pragma unroll
    for (int i = 0; i < 4; ++i) {
        #pragma unroll
        for (int r = 0; r < 4; ++r) {
            const int m = m0 + wm + i*16 + (l >> 4)*4 + r;
            if (m >= Mrows) continue;
            if (MODE == 2) {
                const float wgt = mask[m*4 + e0 + ez];
                #pragma unroll
                for (int j = 0; j < 2; ++j) {
                    const int n = n0 + wn + j*16 + (l & 15);
                    float* o = OUTf + (size_t)m*512 + n;
                    const float v = wgt * acc[i][j][r];
                    *o = first ? v : *o + v;
                }
            } else if (MODE == 5) {
                #pragma unroll
                for (int j = 0; j < 2; ++j) {
                    const int n = n0 + wn + j*16 + (l & 15);
                    OUTf[(size_t)m*512 + n] = acc[i][j][r];
                }
            } else if (MODE == 4) {
                #pragma unroll
                for (int j = 0; j < 2; ++j) {
                    const int n = n0 + wn + j*16 + (l & 15);
                    if (n < CONVD) {
                        OUTu[(size_t)m*ldo + n] = f2bf(acc[i][j][r]);
                    } else if (n < CONVD + NH) {
                        OUT2[(size_t)m*NH + (n - CONVD)] =
                            softplusf(acc[i][j][r] + bias[n - CONVD]);
                    }
                }
            } else {
                #pragma unroll
                for (int j = 0; j < 2; ++j) {
                    const int n = n0 + wn + j*16 + (l & 15);
                    OUTu[(size_t)m*ldo + n] = f2bf(acc[i][j][r]);
                }
            }
        }
    }
}

// ------------------------------------------------------------- combine -----
__global__ void __launch_bounds__(256) combine_kernel(
    const float* __restrict__ EO,    // NEXP x M x 512
    const float* __restrict__ mask,  // M x 4
    float* __restrict__ out)         // M x 512
{
    const int idx = blockIdx.x * 256 + threadIdx.x;
    const int m = idx >> 9;
    float s = 0.f;
    #pragma unroll
    for (int e = 0; e < NEXP; ++e)
        s += mask[m*4 + e] * EO[(size_t)e*S_EO + idx];
    out[idx] = s;
}

// ---------------------------------------- conv4 + SiLU, direct (no LDS) -----
__global__ void __launch_bounds__(256) conv_kernel(
    const u16* __restrict__ XBC,
    u16* __restrict__ XCONV,
    const float* __restrict__ conv_w,
    const float* __restrict__ conv_b,
    int e0)
{
    const int e = blockIdx.y;
    XBC   += (size_t)e * S_XC;
    XCONV += (size_t)e * S_XC;
    const int eg = e0 + e;
    const int idx = blockIdx.x * 256 + threadIdx.x;
    const int NCG = CONVD / 8;
    if (idx >= M_TOK * NCG) return;
    const int cg = idx % NCG;
    const int m  = idx / NCG;
    const int b  = m / L_SEQ, l = m - b*L_SEQ;
    const int c0 = cg * 8;

    const u16* base = XBC + (size_t)b*L_SEQ*CONVD + c0;
    const short8 z8 = {0,0,0,0,0,0,0,0};
    short8 r[4];
    #pragma unroll
    for (int k = 0; k < 4; ++k) {
        const int row = l - 3 + k;
        r[k] = (row >= 0) ? *(const short8*)(base + (size_t)row*CONVD) : z8;
    }
    const float4* wp = (const float4*)(conv_w + ((size_t)eg*CONVD + c0)*4);
    const float*  bp = conv_b + (size_t)eg*CONVD + c0;
    short8 o;
    #pragma unroll
    for (int j = 0; j < 8; ++j) {
        const float4 wj = wp[j];
        float v = bf2f(r[0][j])*wj.x + bf2f(r[1][j])*wj.y
                + bf2f(r[2][j])*wj.z + bf2f(r[3][j])*wj.w + bp[j];
        o[j] = f2bf(siluf(v));
    }
    *(short8*)(XCONV + (size_t)m*CONVD + c0) = o;
}

// --------------------------------------------------- SSD pass 1 (per chunk) -
// 1024 threads / 16 waves, unswizzled LDS (round-18 proven).
__global__ void __launch_bounds__(1024) ssd1_kernel(
    u16* __restrict__ XCONV,
    const float* __restrict__ DT,
    float* __restrict__ Acum,
    u16* __restrict__ Hend,
    float* __restrict__ cbuf,
    const float* __restrict__ A_log,
    const float* __restrict__ Dskip,
    int e0)
{
    const int g = blockIdx.x, h = blockIdx.y;
    const int bz = blockIdx.z;
    const int e = bz >> 2, b = bz & 3;
    XCONV += (size_t)e * S_XC;
    DT    += (size_t)e * S_DT;
    Acum  += (size_t)e * S_AC;
    Hend  += (size_t)e * S_HE;
    cbuf  += (size_t)e * S_CB;
    const int eg = e0 + e;
    const int t = threadIdx.x;
    const int ln = t & 63, w = t >> 6;
    const int rt = w >> 1;
    const int ch = w & 1;
    const int bh = b*NH + h;
    const int l0 = g * TCH;

    __shared__ u16 Bc[TCH][LPAD];
    __shared__ u16 Cc[TCH][LPAD];
    __shared__ u16 Xt[HD][LPAD];
    __shared__ u16 Pb[TCH][LPAD];
    __shared__ float ac[TCH], wj[TCH], dtb[TCH];

    const float Ah = -__expf(A_log[eg*NH + h]);
    const float Dv = Dskip[eg*NH + h];

    {
        const int i = t >> 3, q = t & 7;
        const bool v = (l0 + i) < L_SEQ;
        const u16* src = XCONV + (size_t)(b*L_SEQ + l0 + i) * CONVD;
        const short8 z8 = {0,0,0,0,0,0,0,0};
        #pragma unroll
        for (int u = 0; u < 2; ++u) {
            const int col = q*16 + u*8;
            short8 bv = v ? *(const short8*)(src + 1024 + col) : z8;
            short8 cv = v ? *(const short8*)(src + 1152 + col) : z8;
            *(short8*)&Bc[i][col] = bv;
            *(short8*)&Cc[i][col] = cv;
        }
        {
            short8 xv = v ? *(const short8*)(src + h*HD + q*8) : z8;
            #pragma unroll
            for (int k = 0; k < 8; ++k)
                Xt[q*8 + k][i] = ((const u16*)&xv)[k];
        }
        if (t < TCH) {
            const int l = l0 + t;
            dtb[t] = (l < L_SEQ) ? DT[(size_t)(b*L_SEQ + l)*NH + h] : 0.f;
        }
    }
    __syncthreads();

    if (w == 0) {
        float s0 = dtb[ln] * Ah;
        float s1 = dtb[64 + ln] * Ah;
        #pragma unroll
        for (int o = 1; o < 64; o <<= 1) {
            float v0 = __shfl_up(s0, o);
            float v1 = __shfl_up(s1, o);
            if (ln >= o) { s0 += v0; s1 += v1; }
        }
        s1 += __shfl(s0, 63);
        const float acT = __shfl(s1, 63);
        ac[ln] = s0; ac[64 + ln] = s1;
        wj[ln]      = __expf(acT - s0) * dtb[ln];
        wj[64 + ln] = __expf(acT - s1) * dtb[64 + ln];
        if (l0 + ln < L_SEQ)      Acum[(size_t)bh*L_SEQ + l0 + ln] = s0;
        if (l0 + 64 + ln < L_SEQ) Acum[(size_t)bh*L_SEQ + l0 + 64 + ln] = s1;
        if (ln == 63) cbuf[bh*NC + g] = __expf(acT);
    }
    __syncthreads();

    f32x4 sacc[4];
    #pragma unroll
    for (int c = 0; c < 4; ++c) { sacc[c][0]=0.f; sacc[c][1]=0.f; sacc[c][2]=0.f; sacc[c][3]=0.f; }
    #pragma unroll
    for (int ks = 0; ks < 4; ++ks) {
        short8 afr = *(const short8*)&Cc[rt*16 + (ln & 15)][ks*32 + (ln >> 4)*8];
        #pragma unroll
        for (int c = 0; c < 4; ++c) {
            const int ct = ch*4 + c;
            short8 bfr = *(const short8*)&Bc[ct*16 + (ln & 15)][ks*32 + (ln >> 4)*8];
            sacc[c] = __builtin_amdgcn_mfma_f32_16x16x32_bf16(afr, bfr, sacc[c], 0, 0, 0);
        }
    }
    {
        const int i0 = rt*16 + (ln >> 4)*4;
        float aci[4];
        #pragma unroll
        for (int r = 0; r < 4; ++r) aci[r] = ac[i0 + r];
        #pragma unroll
        for (int c = 0; c < 4; ++c) {
            const int j = (ch*4 + c)*16 + (ln & 15);
            const float acj = ac[j], dtj = dtb[j];
            #pragma unroll
            for (int r = 0; r < 4; ++r) {
                const int i2 = i0 + r;
                float pv = (j <= i2) ? sacc[c][r] * __expf(aci[r] - acj) * dtj : 0.f;
                Pb[i2][j] = f2bf(pv);
            }
        }
    }
    __syncthreads();

    {
        f32x4 yacc[2];
        #pragma unroll
        for (int p = 0; p < 2; ++p) { yacc[p][0]=0.f; yacc[p][1]=0.f; yacc[p][2]=0.f; yacc[p][3]=0.f; }
        #pragma unroll
        for (int ks = 0; ks < 4; ++ks) {
            short8 afr = *(const short8*)&Pb[rt*16 + (ln & 15)][ks*32 + (ln >> 4)*8];
            #pragma unroll
            for (int p = 0; p < 2; ++p) {
                const int pt = ch*2 + p;
                short8 bfr = *(const short8*)&Xt[pt*16 + (ln & 15)][ks*32 + (ln >> 4)*8];
                yacc[p] = __builtin_amdgcn_mfma_f32_16x16x32_bf16(afr, bfr, yacc[p], 0, 0, 0);
            }
        }
        #pragma unroll
        for (int p = 0; p < 2; ++p) {
            const int pp = (ch*2 + p)*16 + (ln & 15);
            #pragma unroll
            for (int r = 0; r < 4; ++r) {
                const int i2 = rt*16 + (ln >> 4)*4 + r;
                const int lg = l0 + i2;
                if (lg < L_SEQ) {
                    const float xv = bf2f(Xt[pp][i2]);
                    XCONV[(size_t)(b*L_SEQ + lg)*CONVD + h*HD + pp] =
                        f2bf(yacc[p][r] + Dv * xv);
                }
            }
        }
    }

    {
        f32x4 hacc[2];
        #pragma unroll
        for (int p = 0; p < 2; ++p) { hacc[p][0]=0.f; hacc[p][1]=0.f; hacc[p][2]=0.f; hacc[p][3]=0.f; }
        #pragma unroll
        for (int ks = 0; ks < 4; ++ks) {
            const int jb = ks*32 + (ln >> 4)*8;
            const int nr = rt*16 + (ln & 15);
            short8 afr;
            #pragma unroll
            for (int jj = 0; jj < 8; ++jj)
                afr[jj] = (short)f2bf(bf2f(Bc[jb + jj][nr]) * wj[jb + jj]);
            #pragma unroll
            for (int p = 0; p < 2; ++p) {
                const int pt = ch*2 + p;
                short8 bfr = *(const short8*)&Xt[pt*16 + (ln & 15)][jb];
                hacc[p] = __builtin_amdgcn_mfma_f32_16x16x32_bf16(afr, bfr, hacc[p], 0, 0, 0);
            }
        }
        u16* Hb = Hend + (size_t)(bh*NC + g) * (TCH*HD);
        #pragma unroll
        for (int p = 0; p < 2; ++p)
            #pragma unroll
            for (int r = 0; r < 4; ++r) {
                const int n = rt*16 + (ln >> 4)*4 + r;
                Hb[n*HD + (ch*2 + p)*16 + (ln & 15)] = f2bf(hacc[p][r]);
            }
    }
}

// --------------------------------------- pass 2: chunk-state propagation ----
__global__ void __launch_bounds__(256) prop_kernel(
    u16* __restrict__ Hend, const float* __restrict__ cbuf)
{
    const int e  = blockIdx.x >> 6;
    const int bh = blockIdx.x & 63;
    Hend += (size_t)e * S_HE;
    cbuf += (size_t)e * S_CB;
    const int t  = threadIdx.x;
    float hs[32];
    #pragma unroll
    for (int j = 0; j < 32; ++j) hs[j] = 0.f;
    for (int g = 0; g < NC - 1; ++g) {
        const float ce = cbuf[bh*NC + g];
        u16* He = Hend + (size_t)(bh*NC + g)*(TCH*HD) + t*32;
        #pragma unroll
        for (int j = 0; j < 32; ++j) {
            const float lo = bf2f(He[j]);
            hs[j] = ce*hs[j] + lo;
            He[j] = f2bf(hs[j]);
        }
    }
}

// --------------------------------------------- pass 3: Y2 = Cs @ h_start ----
__global__ void __launch_bounds__(256) ssd2_kernel(
    u16* __restrict__ XCONV,
    const float* __restrict__ Acum,
    const u16* __restrict__ Hend)
{
    const int g = blockIdx.x + 1, h = blockIdx.y;
    const int bz = blockIdx.z;
    const int e = bz >> 2, b = bz & 3;
    XCONV += (size_t)e * S_XC;
    Acum  += (size_t)e * S_AC;
    Hend  += (size_t)e * S_HE;
    const int t = threadIdx.x, ln = t & 63, w = t >> 6;
    const int bh = b*NH + h;
    const int l0 = g * TCH;

    __shared__ u16 Cs[TCH][LPAD];
    __shared__ u16 Ht[HD][LPAD];

    {
        const int i = t >> 1, q = t & 1;
        const bool v = (l0 + i) < L_SEQ;
        const float eaci = v ? __expf(Acum[(size_t)bh*L_SEQ + l0 + i]) : 0.f;
        const u16* src = XCONV + (size_t)(b*L_SEQ + l0 + i)*CONVD + 1152 + q*64;
        const short8 z8 = {0,0,0,0,0,0,0,0};
        #pragma unroll
        for (int u = 0; u < 8; ++u) {
            short8 cv = v ? *(const short8*)(src + u*8) : z8;
            short8 ov;
            #pragma unroll
            for (int k = 0; k < 8; ++k)
                ov[k] = (short)f2bf(bf2f(((const u16*)&cv)[k]) * eaci);
            *(short8*)&Cs[i][q*64 + u*8] = ov;
        }
    }
    {
        const u16* Hb = Hend + (size_t)(bh*NC + g - 1)*(TCH*HD) + t*32;
        #pragma unroll
        for (int k = 0; k < 32; ++k) {
            const int idx = t*32 + k;
            Ht[idx & 63][idx >> 6] = Hb[k];
        }
    }
    __syncthreads();

    f32x4 acc2[2][4];
    #pragma unroll
    for (int rt = 0; rt < 2; ++rt)
        #pragma unroll
        for (int pt = 0; pt < 4; ++pt) { acc2[rt][pt][0]=0.f; acc2[rt][pt][1]=0.f; acc2[rt][pt][2]=0.f; acc2[rt][pt][3]=0.f; }
    #pragma unroll
    for (int ks = 0; ks < 4; ++ks) {
        short8 af0 = *(const short8*)&Cs[w*32 +      (ln & 15)][ks*32 + (ln >> 4)*8];
        short8 af1 = *(const short8*)&Cs[w*32 + 16 + (ln & 15)][ks*32 + (ln >> 4)*8];
        #pragma unroll
        for (int pt = 0; pt < 4; ++pt) {
            short8 bfr = *(const short8*)&Ht[pt*16 + (ln & 15)][ks*32 + (ln >> 4)*8];
            acc2[0][pt] = __builtin_amdgcn_mfma_f32_16x16x32_bf16(af0, bfr, acc2[0][pt], 0, 0, 0);
            acc2[1][pt] = __builtin_amdgcn_mfma_f32_16x16x32_bf16(af1, bfr, acc2[1][pt], 0, 0, 0);
        }
    }
    #pragma unroll
    for (int rt = 0; rt < 2; ++rt)
        #pragma unroll
        for (int pt = 0; pt < 4; ++pt)
            #pragma unroll
            for (int r = 0; r < 4; ++r) {
                const int i2 = w*32 + rt*16 + (ln >> 4)*4 + r;
                const int lg = l0 + i2;
                if (lg < L_SEQ) {
                    u16* yp = XCONV + (size_t)(b*L_SEQ + lg)*CONVD + h*HD + pt*16 + (ln & 15);
                    *yp = f2bf(bf2f(*yp) + acc2[rt][pt][r]);
                }
            }
}

// ------------------------------------------------- gated RMS norm (bf16) ----
__global__ void __launch_bounds__(256) norm_kernel(
    u16* __restrict__ Ybuf,
    const u16* __restrict__ Z,
    const float* __restrict__ norm_w,
    int e0)
{
    const int e = blockIdx.y;
    Ybuf += (size_t)e * S_XC;
    Z    += (size_t)e * S_ZT;
    const float* nw = norm_w + (size_t)(e0 + e) * DINNER;
    const int row = blockIdx.x;
    const int t = threadIdx.x;
    u16* y = Ybuf + (size_t)row * CONVD;
    const u16* z = Z + (size_t)row * DINNER;

    ushort4 yv = *(const ushort4*)(y + t*4);
    ushort4 zv = *(const ushort4*)(z + t*4);
    float v[4]; float ss = 0.f;
    #pragma unroll
    for (int j = 0; j < 4; ++j) {
        const float zz = bf2f(((const u16*)&zv)[j]);
        const float vv = bf2f(((const u16*)&yv)[j]) * siluf(zz);
        v[j] = vv; ss += vv*vv;
    }
    #pragma unroll
    for (int o = 32; o > 0; o >>= 1) ss += __shfl_down(ss, o);
    __shared__ float wsum[4];
    if ((t & 63) == 0) wsum[t >> 6] = ss;
    __syncthreads();
    const float total = wsum[0] + wsum[1] + wsum[2] + wsum[3];
    const float scale = rsqrtf(total / (float)DINNER + 1e-5f);
    ushort4 ov;
    #pragma unroll
    for (int j = 0; j < 4; ++j)
        ((u16*)&ov)[j] = f2bf(v[j] * scale * nw[t*4 + j]);
    *(ushort4*)(y + t*4) = ov;
}

// ------------------------------------------------------------------ host ----
extern "C" void kernel_launch(void* const* d_in, const int* in_sizes, int n_in,
                              void* d_out, int out_size, void* d_ws, size_t ws_size,
                              hipStream_t stream)
{
    const float* x        = (const float*)d_in[0];
    const float* gate_w   = (const float*)d_in[1];
    const float* gate_b   = (const float*)d_in[2];
    const float* gate_n   = (const float*)d_in[3];
    const float* in_w     = (const float*)d_in[4];
    const float* conv_w   = (const float*)d_in[5];
    const float* conv_b   = (const float*)d_in[6];
    const float* dt_bias  = (const float*)d_in[7];
    const float* A_log    = (const float*)d_in[8];
    const float* Dskip    = (const float*)d_in[9];
    const float* norm_w   = (const float*)d_in[10];
    const float* out_w    = (const float*)d_in[11];
    float* out = (float*)d_out;

    char* ws = (char*)d_ws;
    const size_t NEED_BIG = 189969408;
    const bool big = ws_size >= NEED_BIG;

    if (big) {
        // R1 serves sequentially: XBCraw_all -> Hend_all -> Ztile_all -> EO_all
        u16*   R1     = (u16*)ws;                        //  81,920,000 B
        u16*   XCONV  = (u16*)(ws + 81920000);           //  81,920,000 B
        u16*   xbf    = (u16*)(ws + 163840000);          //   8,192,000 B
        u16*   inwb   = (u16*)(ws + 172032000);          //   9,502,720 B
        u16*   outwb  = (u16*)(ws + 181534720);          //   4,194,304 B
        float* DTb    = (float*)(ws + 185729024);        //   2,048,000 B
        float* Acum   = (float*)(ws + 187777024);        //   2,048,000 B
        float* cbuf   = (float*)(ws + 189825024);        //      16,384 B
        float* maskb  = (float*)(ws + 189841408);        //     128,000 B
        float* EO     = (float*)R1;                      //  65,536,000 B (alias)

        gate_kernel<<<M_TOK, 64, 0, stream>>>(x, gate_w, gate_b, gate_n, maskb);
        cvt_kernel<<<2000, 256, 0, stream>>>(x, xbf, 512000);
        cvt_kernel<<<2320, 256, 0, stream>>>(in_w, inwb, 593920);
        cvt_kernel<<<1024, 256, 0, stream>>>(out_w, outwb, 262144);

        gemm_bb<4><<<dim3(11, 63, NEXP), 512, 0, stream>>>(
            xbf, DMODEL, M_TOK, inwb + (size_t)1024*512, DMODEL, 1296,
            R1, CONVD, nullptr, 0, 0, DTb, dt_bias, 0, S_WI, S_XC, S_DT);
        conv_kernel<<<dim3(5000, NEXP), 256, 0, stream>>>(
            R1, XCONV, conv_w, conv_b, 0);
        ssd1_kernel<<<dim3(NC, NH, BATCH*NEXP), 1024, 0, stream>>>(
            XCONV, DTb, Acum, (u16*)R1, cbuf, A_log, Dskip, 0);
        prop_kernel<<<64*NEXP, 256, 0, stream>>>((u16*)R1, cbuf);
        ssd2_kernel<<<dim3(NC - 1, NH, BATCH*NEXP), 256, 0, stream>>>(
            XCONV, Acum, (const u16*)R1);
        gemm_bb<0><<<dim3(8, 63, NEXP), 512, 0, stream>>>(
            xbf, DMODEL, M_TOK, inwb, DMODEL, DINNER,
            R1, DINNER, nullptr, 0, 0, nullptr, nullptr, 0, S_WI, S_ZT, 0);
        norm_kernel<<<dim3(M_TOK, NEXP), 256, 0, stream>>>(
            XCONV, R1, norm_w, 0);
        // out_proj: batched into EO (R1 dead after norm), then combine.
        // NOTE strideA = S_XC: each expert reads ITS OWN normalized y.
        gemm_bb<5><<<dim3(4, 63, NEXP), 512, 0, stream>>>(
            XCONV, CONVD, M_TOK, outwb, DINNER, DMODEL,
            EO, 512, nullptr, 0, 0, nullptr, nullptr, S_XC, S_WO, S_EO, 0);
        combine_kernel<<<M_TOK*DMODEL/256, 256, 0, stream>>>(EO, maskb, out);
    } else {
        // fallback: per-expert loop (64MB layout)
        u16*   R1     = (u16*)ws;
        u16*   XCONV  = (u16*)(ws + 20480000);
        u16*   xbf    = (u16*)(ws + 40960000);
        u16*   inwb   = (u16*)(ws + 49152000);
        u16*   outwb  = (u16*)(ws + 58654720);
        float* DTb    = (float*)(ws + 62849024);
        float* Acum   = (float*)(ws + 63361024);
        float* cbuf   = (float*)(ws + 63873024);
        float* maskb  = (float*)(ws + 63877120);

        gate_kernel<<<M_TOK, 64, 0, stream>>>(x, gate_w, gate_b, gate_n, maskb);
        cvt_kernel<<<2000, 256, 0, stream>>>(x, xbf, 512000);
        cvt_kernel<<<2320, 256, 0, stream>>>(in_w, inwb, 593920);
        cvt_kernel<<<1024, 256, 0, stream>>>(out_w, outwb, 262144);

        for (int e = 0; e < NEXP; ++e) {
            gemm_bb<4><<<dim3(11, 63, 1), 512, 0, stream>>>(
                xbf, DMODEL, M_TOK,
                inwb + (size_t)e*S_WI + (size_t)1024*512, DMODEL, 1296,
                R1, CONVD, nullptr, 0, 0, DTb, dt_bias + e*NH, 0, 0, 0, 0);
            conv_kernel<<<dim3(5000, 1), 256, 0, stream>>>(
                R1, XCONV, conv_w, conv_b, e);
            ssd1_kernel<<<dim3(NC, NH, BATCH), 1024, 0, stream>>>(
                XCONV, DTb, Acum, (u16*)R1, cbuf, A_log, Dskip, e);
            prop_kernel<<<64, 256, 0, stream>>>((u16*)R1, cbuf);
            ssd2_kernel<<<dim3(NC - 1, NH, BATCH), 256, 0, stream>>>(
                XCONV, Acum, (const u16*)R1);
            gemm_bb<0><<<dim3(8, 63, 1), 512, 0, stream>>>(
                xbf, DMODEL, M_TOK, inwb + (size_t)e*S_WI, DMODEL, DINNER,
                R1, DINNER, nullptr, 0, 0, nullptr, nullptr, 0, 0, 0, 0);
            norm_kernel<<<dim3(M_TOK, 1), 256, 0, stream>>>(
                XCONV, R1, norm_w, e);
            gemm_bb<2><<<dim3(4, 63, 1), 512, 0, stream>>>(
                XCONV, CONVD, M_TOK, outwb + (size_t)e*S_WO, DINNER, DMODEL,
                out, 512, maskb, e, e == 0 ? 1 : 0, nullptr, nullptr, 0, 0, 0, 0);
        }
    }
}

// Round 22
// 567.679 us; speedup vs baseline: 1.5395x; 1.0672x over previous
//
#include <hip/hip_runtime.h>
#include <hip/hip_bf16.h>

#define M_TOK   8000
#define L_SEQ   2000
#define BATCH   4
#define NEXP    4
#define NH      16
#define HD      64
#define DSTATE  128
#define DMODEL  512
#define DINNER  1024
#define CONVD   1280
#define DIN_ALL 2320
#define TCH     128
#define NC      16
#define LPAD    136

// per-expert element strides (big path)
#define S_XC   10240000u
#define S_HE    8388608u
#define S_ZT    8192000u
#define S_DT     128000u
#define S_AC     128000u
#define S_CB       1024u
#define S_WI    1187840u
#define S_WO     524288u
#define S_EO    4096000u   // EO: 8000*512 f32

typedef __attribute__((ext_vector_type(8))) short short8;
typedef __attribute__((ext_vector_type(4))) float f32x4;
typedef unsigned short u16;

__device__ __forceinline__ float siluf(float v) {
    return v / (1.f + __expf(-v));
}
__device__ __forceinline__ float softplusf(float v) {
    return v > 20.f ? v : log1pf(expf(v));
}
__device__ __forceinline__ u16 f2bf(float f) {
    union { float f; unsigned u; } x; x.f = f;
    return (u16)((x.u + 0x7fffu + ((x.u >> 16) & 1u)) >> 16);
}
__device__ __forceinline__ float bf2f(u16 v) {
    union { unsigned u; float f; } x; x.u = ((unsigned)v) << 16; return x.f;
}
__device__ __forceinline__ void gl16(const void* g, void* l) {
    __builtin_amdgcn_global_load_lds(
        (const __attribute__((address_space(1))) void*)g,
        (__attribute__((address_space(3))) void*)l, 16, 0, 0);
}

// ---------------------------------------------------------------- gating ----
__global__ void __launch_bounds__(64) gate_kernel(
    const float* __restrict__ X, const float* __restrict__ GW,
    const float* __restrict__ GB, const float* __restrict__ GN,
    float* __restrict__ mask)
{
    const int m = blockIdx.x;
    const int t = threadIdx.x;
    const float* x = X + (size_t)m * DMODEL;
    float s0 = 0.f, s1 = 0.f, s2 = 0.f, s3 = 0.f;
    for (int k = t; k < DMODEL; k += 64) {
        float xv = x[k];
        s0 += xv * GW[k];
        s1 += xv * GW[512 + k];
        s2 += xv * GW[1024 + k];
        s3 += xv * GW[1536 + k];
    }
    #pragma unroll
    for (int o = 32; o > 0; o >>= 1) {
        s0 += __shfl_down(s0, o);
        s1 += __shfl_down(s1, o);
        s2 += __shfl_down(s2, o);
        s3 += __shfl_down(s3, o);
    }
    if (t == 0) {
        float lg[4] = { s0 + GB[0] + GN[m*4+0]*0.01f,
                        s1 + GB[1] + GN[m*4+1]*0.01f,
                        s2 + GB[2] + GN[m*4+2]*0.01f,
                        s3 + GB[3] + GN[m*4+3]*0.01f };
        float mx = fmaxf(fmaxf(lg[0], lg[1]), fmaxf(lg[2], lg[3]));
        float p[4]; float sum = 0.f;
        #pragma unroll
        for (int e = 0; e < 4; ++e) { p[e] = expf(lg[e] - mx); sum += p[e]; }
        #pragma unroll
        for (int e = 0; e < 4; ++e) p[e] /= sum;
        int i0 = 0;
        #pragma unroll
        for (int e = 1; e < 4; ++e) if (p[e] > p[i0]) i0 = e;
        int i1 = -1;
        #pragma unroll
        for (int e = 0; e < 4; ++e) {
            if (e == i0) continue;
            if (i1 < 0 || p[e] > p[i1]) i1 = e;
        }
        float s2v = p[i0] + p[i1];
        #pragma unroll
        for (int e = 0; e < 4; ++e)
            mask[m*4 + e] = (e == i0 || e == i1) ? p[e] / s2v : 0.f;
    }
}

// ------------------------------------------------------- f32 -> bf16 copy ---
__global__ void __launch_bounds__(256) cvt_kernel(
    const float* __restrict__ src, u16* __restrict__ dst, int n8)
{
    const int i = blockIdx.x * 256 + threadIdx.x;
    if (i >= n8) return;
    const float4 a = ((const float4*)src)[i*2];
    const float4 b = ((const float4*)src)[i*2 + 1];
    short8 o;
    o[0]=f2bf(a.x); o[1]=f2bf(a.y); o[2]=f2bf(a.z); o[3]=f2bf(a.w);
    o[4]=f2bf(b.x); o[5]=f2bf(b.y); o[6]=f2bf(b.z); o[7]=f2bf(b.w);
    ((short8*)dst)[i] = o;
}

// ------------------- bf16 GEMM (8-wave, BK=32 dbuf, 4 blocks/CU) -----------
// 128x128 tile, BK=32, 512 threads / 8 waves, LDS 32KB (dbuf) -> 32 waves/CU.
// Per iter: {stage next (1 gl16/operand/thread) || 8 MFMA} then ONE barrier.
// Expert-batched via blockIdx.z with per-operand strides.
// MODE 0: bf16 stride ldo. MODE 2: f32 512-stride (+)= mask*acc.
// MODE 4: xBC bf16 + dt softplus. MODE 5: f32 plain acc, stride 512 (EO).
template<int MODE>
__global__ void __launch_bounds__(512) gemm_bb(
    const u16* __restrict__ A, int lda, int Mrows,
    const u16* __restrict__ B, int K, int Nrows,
    void* __restrict__ OUT, int ldo,
    const float* __restrict__ mask, int e0, int first,
    float* __restrict__ OUT2, const float* __restrict__ bias,
    size_t strideA, size_t strideB, size_t strideO, size_t strideO2)
{
    __shared__ u16 As[2][128][32];
    __shared__ u16 Bs[2][128][32];
    const int t  = threadIdx.x;
    const int ez = blockIdx.z;
    A += (size_t)ez * strideA;
    B += (size_t)ez * strideB;
    u16*   OUTu = (u16*)OUT + (size_t)ez * strideO;
    float* OUTf = (float*)OUT + (size_t)ez * strideO;
    if (MODE == 4) { OUT2 += (size_t)ez * strideO2; bias += (size_t)ez * NH; }
    const int nbx = gridDim.x;
    const int nwg = nbx * gridDim.y;
    int bid = blockIdx.y * nbx + blockIdx.x;
    {
        const int xcd = bid & 7, lo = bid >> 3;
        const int q8 = nwg >> 3, r8 = nwg & 7;
        bid = (xcd < r8 ? xcd*(q8+1) : r8*(q8+1) + (xcd - r8)*q8) + lo;
    }
    const int m0 = (bid / nbx) * 128;
    const int n0 = (bid % nbx) * 128;
    const int w  = t >> 6, l = t & 63;
    const int wm = (w >> 2) * 64, wn = (w & 3) * 32;
    const int sr = l >> 2;           // 0..15: row within wave's 16-row chunk
    const int sc = (l & 3) * 8;      // bf16 col 0,8,16,24

    f32x4 acc[4][2];
    #pragma unroll
    for (int i = 0; i < 4; ++i)
        #pragma unroll
        for (int j = 0; j < 2; ++j) {
            acc[i][j][0]=0.f; acc[i][j][1]=0.f; acc[i][j][2]=0.f; acc[i][j][3]=0.f;
        }

    const int nk = K >> 5;
    const int srow = w*16 + sr;      // 0..127, wave-uniform base + lane part
    // prologue: stage tile 0 into buffer 0
    {
        int ga = m0 + srow; if (ga >= Mrows) ga = Mrows - 1;
        gl16(A + (size_t)ga*lda + sc, &As[0][w*16][0]);
        int gb = n0 + srow; if (gb >= Nrows) gb = Nrows - 1;
        gl16(B + (size_t)gb*K + sc, &Bs[0][w*16][0]);
    }
    __syncthreads();

    for (int kt = 0; kt < nk; ++kt) {
        const int cur = kt & 1;
        if (kt + 1 < nk) {
            const int nxt = cur ^ 1;
            const int k0 = (kt + 1) << 5;
            int ga = m0 + srow; if (ga >= Mrows) ga = Mrows - 1;
            gl16(A + (size_t)ga*lda + k0 + sc, &As[nxt][w*16][0]);
            int gb = n0 + srow; if (gb >= Nrows) gb = Nrows - 1;
            gl16(B + (size_t)gb*K + k0 + sc, &Bs[nxt][w*16][0]);
        }
        {
            short8 af[4], bf[2];
            const int ko = (l >> 4)*8;
            #pragma unroll
            for (int i = 0; i < 4; ++i)
                af[i] = *(const short8*)&As[cur][wm + i*16 + (l & 15)][ko];
            #pragma unroll
            for (int j = 0; j < 2; ++j)
                bf[j] = *(const short8*)&Bs[cur][wn + j*16 + (l & 15)][ko];
            #pragma unroll
            for (int i = 0; i < 4; ++i)
                #pragma unroll
                for (int j = 0; j < 2; ++j)
                    acc[i][j] = __builtin_amdgcn_mfma_f32_16x16x32_bf16(
                        af[i], bf[j], acc[i][j], 0, 0, 0);
        }
        __syncthreads();   // next-tile loads landed during MFMA
    }

    #pragma unroll
    for (int i = 0; i < 4; ++i) {
        #pragma unroll
        for (int r = 0; r < 4; ++r) {
            const int m = m0 + wm + i*16 + (l >> 4)*4 + r;
            if (m >= Mrows) continue;
            if (MODE == 2) {
                const float wgt = mask[m*4 + e0 + ez];
                #pragma unroll
                for (int j = 0; j < 2; ++j) {
                    const int n = n0 + wn + j*16 + (l & 15);
                    float* o = OUTf + (size_t)m*512 + n;
                    const float v = wgt * acc[i][j][r];
                    *o = first ? v : *o + v;
                }
            } else if (MODE == 5) {
                #pragma unroll
                for (int j = 0; j < 2; ++j) {
                    const int n = n0 + wn + j*16 + (l & 15);
                    OUTf[(size_t)m*512 + n] = acc[i][j][r];
                }
            } else if (MODE == 4) {
                #pragma unroll
                for (int j = 0; j < 2; ++j) {
                    const int n = n0 + wn + j*16 + (l & 15);
                    if (n < CONVD) {
                        OUTu[(size_t)m*ldo + n] = f2bf(acc[i][j][r]);
                    } else if (n < CONVD + NH) {
                        OUT2[(size_t)m*NH + (n - CONVD)] =
                            softplusf(acc[i][j][r] + bias[n - CONVD]);
                    }
                }
            } else {
                #pragma unroll
                for (int j = 0; j < 2; ++j) {
                    const int n = n0 + wn + j*16 + (l & 15);
                    OUTu[(size_t)m*ldo + n] = f2bf(acc[i][j][r]);
                }
            }
        }
    }
}

// ------------------------------------------------------------- combine -----
__global__ void __launch_bounds__(256) combine_kernel(
    const float* __restrict__ EO,    // NEXP x M x 512
    const float* __restrict__ mask,  // M x 4
    float* __restrict__ out)         // M x 512
{
    const int idx = blockIdx.x * 256 + threadIdx.x;
    const int m = idx >> 9;
    float s = 0.f;
    #pragma unroll
    for (int e = 0; e < NEXP; ++e)
        s += mask[m*4 + e] * EO[(size_t)e*S_EO + idx];
    out[idx] = s;
}

// ---------------------------------------- conv4 + SiLU, direct (no LDS) -----
__global__ void __launch_bounds__(256) conv_kernel(
    const u16* __restrict__ XBC,
    u16* __restrict__ XCONV,
    const float* __restrict__ conv_w,
    const float* __restrict__ conv_b,
    int e0)
{
    const int e = blockIdx.y;
    XBC   += (size_t)e * S_XC;
    XCONV += (size_t)e * S_XC;
    const int eg = e0 + e;
    const int idx = blockIdx.x * 256 + threadIdx.x;
    const int NCG = CONVD / 8;
    if (idx >= M_TOK * NCG) return;
    const int cg = idx % NCG;
    const int m  = idx / NCG;
    const int b  = m / L_SEQ, l = m - b*L_SEQ;
    const int c0 = cg * 8;

    const u16* base = XBC + (size_t)b*L_SEQ*CONVD + c0;
    const short8 z8 = {0,0,0,0,0,0,0,0};
    short8 r[4];
    #pragma unroll
    for (int k = 0; k < 4; ++k) {
        const int row = l - 3 + k;
        r[k] = (row >= 0) ? *(const short8*)(base + (size_t)row*CONVD) : z8;
    }
    const float4* wp = (const float4*)(conv_w + ((size_t)eg*CONVD + c0)*4);
    const float*  bp = conv_b + (size_t)eg*CONVD + c0;
    short8 o;
    #pragma unroll
    for (int j = 0; j < 8; ++j) {
        const float4 wj = wp[j];
        float v = bf2f(r[0][j])*wj.x + bf2f(r[1][j])*wj.y
                + bf2f(r[2][j])*wj.z + bf2f(r[3][j])*wj.w + bp[j];
        o[j] = f2bf(siluf(v));
    }
    *(short8*)(XCONV + (size_t)m*CONVD + c0) = o;
}

// --------------------------------------------------- SSD pass 1 (per chunk) -
// 1024 threads / 16 waves, unswizzled LDS (round-18 proven).
__global__ void __launch_bounds__(1024) ssd1_kernel(
    u16* __restrict__ XCONV,
    const float* __restrict__ DT,
    float* __restrict__ Acum,
    u16* __restrict__ Hend,
    float* __restrict__ cbuf,
    const float* __restrict__ A_log,
    const float* __restrict__ Dskip,
    int e0)
{
    const int g = blockIdx.x, h = blockIdx.y;
    const int bz = blockIdx.z;
    const int e = bz >> 2, b = bz & 3;
    XCONV += (size_t)e * S_XC;
    DT    += (size_t)e * S_DT;
    Acum  += (size_t)e * S_AC;
    Hend  += (size_t)e * S_HE;
    cbuf  += (size_t)e * S_CB;
    const int eg = e0 + e;
    const int t = threadIdx.x;
    const int ln = t & 63, w = t >> 6;
    const int rt = w >> 1;
    const int ch = w & 1;
    const int bh = b*NH + h;
    const int l0 = g * TCH;

    __shared__ u16 Bc[TCH][LPAD];
    __shared__ u16 Cc[TCH][LPAD];
    __shared__ u16 Xt[HD][LPAD];
    __shared__ u16 Pb[TCH][LPAD];
    __shared__ float ac[TCH], wj[TCH], dtb[TCH];

    const float Ah = -__expf(A_log[eg*NH + h]);
    const float Dv = Dskip[eg*NH + h];

    {
        const int i = t >> 3, q = t & 7;
        const bool v = (l0 + i) < L_SEQ;
        const u16* src = XCONV + (size_t)(b*L_SEQ + l0 + i) * CONVD;
        const short8 z8 = {0,0,0,0,0,0,0,0};
        #pragma unroll
        for (int u = 0; u < 2; ++u) {
            const int col = q*16 + u*8;
            short8 bv = v ? *(const short8*)(src + 1024 + col) : z8;
            short8 cv = v ? *(const short8*)(src + 1152 + col) : z8;
            *(short8*)&Bc[i][col] = bv;
            *(short8*)&Cc[i][col] = cv;
        }
        {
            short8 xv = v ? *(const short8*)(src + h*HD + q*8) : z8;
            #pragma unroll
            for (int k = 0; k < 8; ++k)
                Xt[q*8 + k][i] = ((const u16*)&xv)[k];
        }
        if (t < TCH) {
            const int l = l0 + t;
            dtb[t] = (l < L_SEQ) ? DT[(size_t)(b*L_SEQ + l)*NH + h] : 0.f;
        }
    }
    __syncthreads();

    if (w == 0) {
        float s0 = dtb[ln] * Ah;
        float s1 = dtb[64 + ln] * Ah;
        #pragma unroll
        for (int o = 1; o < 64; o <<= 1) {
            float v0 = __shfl_up(s0, o);
            float v1 = __shfl_up(s1, o);
            if (ln >= o) { s0 += v0; s1 += v1; }
        }
        s1 += __shfl(s0, 63);
        const float acT = __shfl(s1, 63);
        ac[ln] = s0; ac[64 + ln] = s1;
        wj[ln]      = __expf(acT - s0) * dtb[ln];
        wj[64 + ln] = __expf(acT - s1) * dtb[64 + ln];
        if (l0 + ln < L_SEQ)      Acum[(size_t)bh*L_SEQ + l0 + ln] = s0;
        if (l0 + 64 + ln < L_SEQ) Acum[(size_t)bh*L_SEQ + l0 + 64 + ln] = s1;
        if (ln == 63) cbuf[bh*NC + g] = __expf(acT);
    }
    __syncthreads();

    f32x4 sacc[4];
    #pragma unroll
    for (int c = 0; c < 4; ++c) { sacc[c][0]=0.f; sacc[c][1]=0.f; sacc[c][2]=0.f; sacc[c][3]=0.f; }
    #pragma unroll
    for (int ks = 0; ks < 4; ++ks) {
        short8 afr = *(const short8*)&Cc[rt*16 + (ln & 15)][ks*32 + (ln >> 4)*8];
        #pragma unroll
        for (int c = 0; c < 4; ++c) {
            const int ct = ch*4 + c;
            short8 bfr = *(const short8*)&Bc[ct*16 + (ln & 15)][ks*32 + (ln >> 4)*8];
            sacc[c] = __builtin_amdgcn_mfma_f32_16x16x32_bf16(afr, bfr, sacc[c], 0, 0, 0);
        }
    }
    {
        const int i0 = rt*16 + (ln >> 4)*4;
        float aci[4];
        #pragma unroll
        for (int r = 0; r < 4; ++r) aci[r] = ac[i0 + r];
        #pragma unroll
        for (int c = 0; c < 4; ++c) {
            const int j = (ch*4 + c)*16 + (ln & 15);
            const float acj = ac[j], dtj = dtb[j];
            #pragma unroll
            for (int r = 0; r < 4; ++r) {
                const int i2 = i0 + r;
                float pv = (j <= i2) ? sacc[c][r] * __expf(aci[r] - acj) * dtj : 0.f;
                Pb[i2][j] = f2bf(pv);
            }
        }
    }
    __syncthreads();

    {
        f32x4 yacc[2];
        #pragma unroll
        for (int p = 0; p < 2; ++p) { yacc[p][0]=0.f; yacc[p][1]=0.f; yacc[p][2]=0.f; yacc[p][3]=0.f; }
        #pragma unroll
        for (int ks = 0; ks < 4; ++ks) {
            short8 afr = *(const short8*)&Pb[rt*16 + (ln & 15)][ks*32 + (ln >> 4)*8];
            #pragma unroll
            for (int p = 0; p < 2; ++p) {
                const int pt = ch*2 + p;
                short8 bfr = *(const short8*)&Xt[pt*16 + (ln & 15)][ks*32 + (ln >> 4)*8];
                yacc[p] = __builtin_amdgcn_mfma_f32_16x16x32_bf16(afr, bfr, yacc[p], 0, 0, 0);
            }
        }
        #pragma unroll
        for (int p = 0; p < 2; ++p) {
            const int pp = (ch*2 + p)*16 + (ln & 15);
            #pragma unroll
            for (int r = 0; r < 4; ++r) {
                const int i2 = rt*16 + (ln >> 4)*4 + r;
                const int lg = l0 + i2;
                if (lg < L_SEQ) {
                    const float xv = bf2f(Xt[pp][i2]);
                    XCONV[(size_t)(b*L_SEQ + lg)*CONVD + h*HD + pp] =
                        f2bf(yacc[p][r] + Dv * xv);
                }
            }
        }
    }

    {
        f32x4 hacc[2];
        #pragma unroll
        for (int p = 0; p < 2; ++p) { hacc[p][0]=0.f; hacc[p][1]=0.f; hacc[p][2]=0.f; hacc[p][3]=0.f; }
        #pragma unroll
        for (int ks = 0; ks < 4; ++ks) {
            const int jb = ks*32 + (ln >> 4)*8;
            const int nr = rt*16 + (ln & 15);
            short8 afr;
            #pragma unroll
            for (int jj = 0; jj < 8; ++jj)
                afr[jj] = (short)f2bf(bf2f(Bc[jb + jj][nr]) * wj[jb + jj]);
            #pragma unroll
            for (int p = 0; p < 2; ++p) {
                const int pt = ch*2 + p;
                short8 bfr = *(const short8*)&Xt[pt*16 + (ln & 15)][jb];
                hacc[p] = __builtin_amdgcn_mfma_f32_16x16x32_bf16(afr, bfr, hacc[p], 0, 0, 0);
            }
        }
        u16* Hb = Hend + (size_t)(bh*NC + g) * (TCH*HD);
        #pragma unroll
        for (int p = 0; p < 2; ++p)
            #pragma unroll
            for (int r = 0; r < 4; ++r) {
                const int n = rt*16 + (ln >> 4)*4 + r;
                Hb[n*HD + (ch*2 + p)*16 + (ln & 15)] = f2bf(hacc[p][r]);
            }
    }
}

// --------------------------------------- pass 2: chunk-state propagation ----
__global__ void __launch_bounds__(256) prop_kernel(
    u16* __restrict__ Hend, const float* __restrict__ cbuf)
{
    const int e  = blockIdx.x >> 6;
    const int bh = blockIdx.x & 63;
    Hend += (size_t)e * S_HE;
    cbuf += (size_t)e * S_CB;
    const int t  = threadIdx.x;
    float hs[32];
    #pragma unroll
    for (int j = 0; j < 32; ++j) hs[j] = 0.f;
    for (int g = 0; g < NC - 1; ++g) {
        const float ce = cbuf[bh*NC + g];
        u16* He = Hend + (size_t)(bh*NC + g)*(TCH*HD) + t*32;
        #pragma unroll
        for (int j = 0; j < 32; ++j) {
            const float lo = bf2f(He[j]);
            hs[j] = ce*hs[j] + lo;
            He[j] = f2bf(hs[j]);
        }
    }
}

// --------------------------------------------- pass 3: Y2 = Cs @ h_start ----
__global__ void __launch_bounds__(256) ssd2_kernel(
    u16* __restrict__ XCONV,
    const float* __restrict__ Acum,
    const u16* __restrict__ Hend)
{
    const int g = blockIdx.x + 1, h = blockIdx.y;
    const int bz = blockIdx.z;
    const int e = bz >> 2, b = bz & 3;
    XCONV += (size_t)e * S_XC;
    Acum  += (size_t)e * S_AC;
    Hend  += (size_t)e * S_HE;
    const int t = threadIdx.x, ln = t & 63, w = t >> 6;
    const int bh = b*NH + h;
    const int l0 = g * TCH;

    __shared__ u16 Cs[TCH][LPAD];
    __shared__ u16 Ht[HD][LPAD];

    {
        const int i = t >> 1, q = t & 1;
        const bool v = (l0 + i) < L_SEQ;
        const float eaci = v ? __expf(Acum[(size_t)bh*L_SEQ + l0 + i]) : 0.f;
        const u16* src = XCONV + (size_t)(b*L_SEQ + l0 + i)*CONVD + 1152 + q*64;
        const short8 z8 = {0,0,0,0,0,0,0,0};
        #pragma unroll
        for (int u = 0; u < 8; ++u) {
            short8 cv = v ? *(const short8*)(src + u*8) : z8;
            short8 ov;
            #pragma unroll
            for (int k = 0; k < 8; ++k)
                ov[k] = (short)f2bf(bf2f(((const u16*)&cv)[k]) * eaci);
            *(short8*)&Cs[i][q*64 + u*8] = ov;
        }
    }
    {
        const u16* Hb = Hend + (size_t)(bh*NC + g - 1)*(TCH*HD) + t*32;
        #pragma unroll
        for (int k = 0; k < 32; ++k) {
            const int idx = t*32 + k;
            Ht[idx & 63][idx >> 6] = Hb[k];
        }
    }
    __syncthreads();

    f32x4 acc2[2][4];
    #pragma unroll
    for (int rt = 0; rt < 2; ++rt)
        #pragma unroll
        for (int pt = 0; pt < 4; ++pt) { acc2[rt][pt][0]=0.f; acc2[rt][pt][1]=0.f; acc2[rt][pt][2]=0.f; acc2[rt][pt][3]=0.f; }
    #pragma unroll
    for (int ks = 0; ks < 4; ++ks) {
        short8 af0 = *(const short8*)&Cs[w*32 +      (ln & 15)][ks*32 + (ln >> 4)*8];
        short8 af1 = *(const short8*)&Cs[w*32 + 16 + (ln & 15)][ks*32 + (ln >> 4)*8];
        #pragma unroll
        for (int pt = 0; pt < 4; ++pt) {
            short8 bfr = *(const short8*)&Ht[pt*16 + (ln & 15)][ks*32 + (ln >> 4)*8];
            acc2[0][pt] = __builtin_amdgcn_mfma_f32_16x16x32_bf16(af0, bfr, acc2[0][pt], 0, 0, 0);
            acc2[1][pt] = __builtin_amdgcn_mfma_f32_16x16x32_bf16(af1, bfr, acc2[1][pt], 0, 0, 0);
        }
    }
    #pragma unroll
    for (int rt = 0; rt < 2; ++rt)
        #pragma unroll
        for (int pt = 0; pt < 4; ++pt)
            #pragma unroll
            for (int r = 0; r < 4; ++r) {
                const int i2 = w*32 + rt*16 + (ln >> 4)*4 + r;
                const int lg = l0 + i2;
                if (lg < L_SEQ) {
                    u16* yp = XCONV + (size_t)(b*L_SEQ + lg)*CONVD + h*HD + pt*16 + (ln & 15);
                    *yp = f2bf(bf2f(*yp) + acc2[rt][pt][r]);
                }
            }
}

// ------------------------------------------------- gated RMS norm (bf16) ----
__global__ void __launch_bounds__(256) norm_kernel(
    u16* __restrict__ Ybuf,
    const u16* __restrict__ Z,
    const float* __restrict__ norm_w,
    int e0)
{
    const int e = blockIdx.y;
    Ybuf += (size_t)e * S_XC;
    Z    += (size_t)e * S_ZT;
    const float* nw = norm_w + (size_t)(e0 + e) * DINNER;
    const int row = blockIdx.x;
    const int t = threadIdx.x;
    u16* y = Ybuf + (size_t)row * CONVD;
    const u16* z = Z + (size_t)row * DINNER;

    ushort4 yv = *(const ushort4*)(y + t*4);
    ushort4 zv = *(const ushort4*)(z + t*4);
    float v[4]; float ss = 0.f;
    #pragma unroll
    for (int j = 0; j < 4; ++j) {
        const float zz = bf2f(((const u16*)&zv)[j]);
        const float vv = bf2f(((const u16*)&yv)[j]) * siluf(zz);
        v[j] = vv; ss += vv*vv;
    }
    #pragma unroll
    for (int o = 32; o > 0; o >>= 1) ss += __shfl_down(ss, o);
    __shared__ float wsum[4];
    if ((t & 63) == 0) wsum[t >> 6] = ss;
    __syncthreads();
    const float total = wsum[0] + wsum[1] + wsum[2] + wsum[3];
    const float scale = rsqrtf(total / (float)DINNER + 1e-5f);
    ushort4 ov;
    #pragma unroll
    for (int j = 0; j < 4; ++j)
        ((u16*)&ov)[j] = f2bf(v[j] * scale * nw[t*4 + j]);
    *(ushort4*)(y + t*4) = ov;
}

// ------------------------------------------------------------------ host ----
extern "C" void kernel_launch(void* const* d_in, const int* in_sizes, int n_in,
                              void* d_out, int out_size, void* d_ws, size_t ws_size,
                              hipStream_t stream)
{
    const float* x        = (const float*)d_in[0];
    const float* gate_w   = (const float*)d_in[1];
    const float* gate_b   = (const float*)d_in[2];
    const float* gate_n   = (const float*)d_in[3];
    const float* in_w     = (const float*)d_in[4];
    const float* conv_w   = (const float*)d_in[5];
    const float* conv_b   = (const float*)d_in[6];
    const float* dt_bias  = (const float*)d_in[7];
    const float* A_log    = (const float*)d_in[8];
    const float* Dskip    = (const float*)d_in[9];
    const float* norm_w   = (const float*)d_in[10];
    const float* out_w    = (const float*)d_in[11];
    float* out = (float*)d_out;

    char* ws = (char*)d_ws;
    const size_t NEED_BIG = 189969408;
    const bool big = ws_size >= NEED_BIG;

    if (big) {
        // R1 serves sequentially: XBCraw_all -> Hend_all -> Ztile_all -> EO_all
        u16*   R1     = (u16*)ws;                        //  81,920,000 B
        u16*   XCONV  = (u16*)(ws + 81920000);           //  81,920,000 B
        u16*   xbf    = (u16*)(ws + 163840000);          //   8,192,000 B
        u16*   inwb   = (u16*)(ws + 172032000);          //   9,502,720 B
        u16*   outwb  = (u16*)(ws + 181534720);          //   4,194,304 B
        float* DTb    = (float*)(ws + 185729024);        //   2,048,000 B
        float* Acum   = (float*)(ws + 187777024);        //   2,048,000 B
        float* cbuf   = (float*)(ws + 189825024);        //      16,384 B
        float* maskb  = (float*)(ws + 189841408);        //     128,000 B
        float* EO     = (float*)R1;                      //  65,536,000 B (alias)

        gate_kernel<<<M_TOK, 64, 0, stream>>>(x, gate_w, gate_b, gate_n, maskb);
        cvt_kernel<<<2000, 256, 0, stream>>>(x, xbf, 512000);
        cvt_kernel<<<2320, 256, 0, stream>>>(in_w, inwb, 593920);
        cvt_kernel<<<1024, 256, 0, stream>>>(out_w, outwb, 262144);

        gemm_bb<4><<<dim3(11, 63, NEXP), 512, 0, stream>>>(
            xbf, DMODEL, M_TOK, inwb + (size_t)1024*512, DMODEL, 1296,
            R1, CONVD, nullptr, 0, 0, DTb, dt_bias, 0, S_WI, S_XC, S_DT);
        conv_kernel<<<dim3(5000, NEXP), 256, 0, stream>>>(
            R1, XCONV, conv_w, conv_b, 0);
        ssd1_kernel<<<dim3(NC, NH, BATCH*NEXP), 1024, 0, stream>>>(
            XCONV, DTb, Acum, (u16*)R1, cbuf, A_log, Dskip, 0);
        prop_kernel<<<64*NEXP, 256, 0, stream>>>((u16*)R1, cbuf);
        ssd2_kernel<<<dim3(NC - 1, NH, BATCH*NEXP), 256, 0, stream>>>(
            XCONV, Acum, (const u16*)R1);
        gemm_bb<0><<<dim3(8, 63, NEXP), 512, 0, stream>>>(
            xbf, DMODEL, M_TOK, inwb, DMODEL, DINNER,
            R1, DINNER, nullptr, 0, 0, nullptr, nullptr, 0, S_WI, S_ZT, 0);
        norm_kernel<<<dim3(M_TOK, NEXP), 256, 0, stream>>>(
            XCONV, R1, norm_w, 0);
        // out_proj: batched into EO (R1 dead after norm), then combine.
        gemm_bb<5><<<dim3(4, 63, NEXP), 512, 0, stream>>>(
            XCONV, CONVD, M_TOK, outwb, DINNER, DMODEL,
            EO, 512, nullptr, 0, 0, nullptr, nullptr, S_XC, S_WO, S_EO, 0);
        combine_kernel<<<M_TOK*DMODEL/256, 256, 0, stream>>>(EO, maskb, out);
    } else {
        // fallback: per-expert loop (64MB layout)
        u16*   R1     = (u16*)ws;
        u16*   XCONV  = (u16*)(ws + 20480000);
        u16*   xbf    = (u16*)(ws + 40960000);
        u16*   inwb   = (u16*)(ws + 49152000);
        u16*   outwb  = (u16*)(ws + 58654720);
        float* DTb    = (float*)(ws + 62849024);
        float* Acum   = (float*)(ws + 63361024);
        float* cbuf   = (float*)(ws + 63873024);
        float* maskb  = (float*)(ws + 63877120);

        gate_kernel<<<M_TOK, 64, 0, stream>>>(x, gate_w, gate_b, gate_n, maskb);
        cvt_kernel<<<2000, 256, 0, stream>>>(x, xbf, 512000);
        cvt_kernel<<<2320, 256, 0, stream>>>(in_w, inwb, 593920);
        cvt_kernel<<<1024, 256, 0, stream>>>(out_w, outwb, 262144);

        for (int e = 0; e < NEXP; ++e) {
            gemm_bb<4><<<dim3(11, 63, 1), 512, 0, stream>>>(
                xbf, DMODEL, M_TOK,
                inwb + (size_t)e*S_WI + (size_t)1024*512, DMODEL, 1296,
                R1, CONVD, nullptr, 0, 0, DTb, dt_bias + e*NH, 0, 0, 0, 0);
            conv_kernel<<<dim3(5000, 1), 256, 0, stream>>>(
                R1, XCONV, conv_w, conv_b, e);
            ssd1_kernel<<<dim3(NC, NH, BATCH), 1024, 0, stream>>>(
                XCONV, DTb, Acum, (u16*)R1, cbuf, A_log, Dskip, e);
            prop_kernel<<<64, 256, 0, stream>>>((u16*)R1, cbuf);
            ssd2_kernel<<<dim3(NC - 1, NH, BATCH), 256, 0, stream>>>(
                XCONV, Acum, (const u16*)R1);
            gemm_bb<0><<<dim3(8, 63, 1), 512, 0, stream>>>(
                xbf, DMODEL, M_TOK, inwb + (size_t)e*S_WI, DMODEL, DINNER,
                R1, DINNER, nullptr, 0, 0, nullptr, nullptr, 0, 0, 0, 0);
            norm_kernel<<<dim3(M_TOK, 1), 256, 0, stream>>>(
                XCONV, R1, norm_w, e);
            gemm_bb<2><<<dim3(4, 63, 1), 512, 0, stream>>>(
                XCONV, CONVD, M_TOK, outwb + (size_t)e*S_WO, DINNER, DMODEL,
                out, 512, maskb, e, e == 0 ? 1 : 0, nullptr, nullptr, 0, 0, 0, 0);
        }
    }
}

// Round 23
// 567.121 us; speedup vs baseline: 1.5410x; 1.0010x over previous
//
#include <hip/hip_runtime.h>
#include <hip/hip_bf16.h>

#define M_TOK   8000
#define L_SEQ   2000
#define BATCH   4
#define NEXP    4
#define NH      16
#define HD      64
#define DSTATE  128
#define DMODEL  512
#define DINNER  1024
#define CONVD   1280
#define DIN_ALL 2320
#define TCH     128
#define NC      16
#define LPAD    136

// per-expert element strides (big path)
#define S_XC   10240000u
#define S_HE    8388608u
#define S_ZT    8192000u
#define S_DT     128000u
#define S_AC     128000u
#define S_CB       1024u
#define S_WI    1187840u
#define S_WO     524288u
#define S_EO    4096000u   // EO: 8000*512 f32

typedef __attribute__((ext_vector_type(8))) short short8;
typedef __attribute__((ext_vector_type(4))) float f32x4;
typedef unsigned short u16;

__device__ __forceinline__ float siluf(float v) {
    return v / (1.f + __expf(-v));
}
__device__ __forceinline__ float softplusf(float v) {
    return v > 20.f ? v : log1pf(expf(v));
}
__device__ __forceinline__ u16 f2bf(float f) {
    union { float f; unsigned u; } x; x.f = f;
    return (u16)((x.u + 0x7fffu + ((x.u >> 16) & 1u)) >> 16);
}
__device__ __forceinline__ float bf2f(u16 v) {
    union { unsigned u; float f; } x; x.u = ((unsigned)v) << 16; return x.f;
}
__device__ __forceinline__ void gl16(const void* g, void* l) {
    __builtin_amdgcn_global_load_lds(
        (const __attribute__((address_space(1))) void*)g,
        (__attribute__((address_space(3))) void*)l, 16, 0, 0);
}
// LDS col-swizzle key for [row][LPAD] tiles: XOR multiples of 16 shorts.
// Involution: write and read sides use the same row-derived key.
#define SWK(row) ((((row) >> 3) & 7) << 4)

// ---------------------------------------------------------------- gating ----
__global__ void __launch_bounds__(64) gate_kernel(
    const float* __restrict__ X, const float* __restrict__ GW,
    const float* __restrict__ GB, const float* __restrict__ GN,
    float* __restrict__ mask)
{
    const int m = blockIdx.x;
    const int t = threadIdx.x;
    const float* x = X + (size_t)m * DMODEL;
    float s0 = 0.f, s1 = 0.f, s2 = 0.f, s3 = 0.f;
    for (int k = t; k < DMODEL; k += 64) {
        float xv = x[k];
        s0 += xv * GW[k];
        s1 += xv * GW[512 + k];
        s2 += xv * GW[1024 + k];
        s3 += xv * GW[1536 + k];
    }
    #pragma unroll
    for (int o = 32; o > 0; o >>= 1) {
        s0 += __shfl_down(s0, o);
        s1 += __shfl_down(s1, o);
        s2 += __shfl_down(s2, o);
        s3 += __shfl_down(s3, o);
    }
    if (t == 0) {
        float lg[4] = { s0 + GB[0] + GN[m*4+0]*0.01f,
                        s1 + GB[1] + GN[m*4+1]*0.01f,
                        s2 + GB[2] + GN[m*4+2]*0.01f,
                        s3 + GB[3] + GN[m*4+3]*0.01f };
        float mx = fmaxf(fmaxf(lg[0], lg[1]), fmaxf(lg[2], lg[3]));
        float p[4]; float sum = 0.f;
        #pragma unroll
        for (int e = 0; e < 4; ++e) { p[e] = expf(lg[e] - mx); sum += p[e]; }
        #pragma unroll
        for (int e = 0; e < 4; ++e) p[e] /= sum;
        int i0 = 0;
        #pragma unroll
        for (int e = 1; e < 4; ++e) if (p[e] > p[i0]) i0 = e;
        int i1 = -1;
        #pragma unroll
        for (int e = 0; e < 4; ++e) {
            if (e == i0) continue;
            if (i1 < 0 || p[e] > p[i1]) i1 = e;
        }
        float s2v = p[i0] + p[i1];
        #pragma unroll
        for (int e = 0; e < 4; ++e)
            mask[m*4 + e] = (e == i0 || e == i1) ? p[e] / s2v : 0.f;
    }
}

// ------------------------------------------------------- f32 -> bf16 copy ---
__global__ void __launch_bounds__(256) cvt_kernel(
    const float* __restrict__ src, u16* __restrict__ dst, int n8)
{
    const int i = blockIdx.x * 256 + threadIdx.x;
    if (i >= n8) return;
    const float4 a = ((const float4*)src)[i*2];
    const float4 b = ((const float4*)src)[i*2 + 1];
    short8 o;
    o[0]=f2bf(a.x); o[1]=f2bf(a.y); o[2]=f2bf(a.z); o[3]=f2bf(a.w);
    o[4]=f2bf(b.x); o[5]=f2bf(b.y); o[6]=f2bf(b.z); o[7]=f2bf(b.w);
    ((short8*)dst)[i] = o;
}

// ------------------- bf16 GEMM (8-wave, BK=32 dbuf, 4 blocks/CU) -----------
// MODE 0: bf16 stride ldo. MODE 2: f32 512-stride (+)= mask*acc.
// MODE 4: xBC bf16 + dt softplus. MODE 5: f32 plain acc, stride 512 (EO).
template<int MODE>
__global__ void __launch_bounds__(512) gemm_bb(
    const u16* __restrict__ A, int lda, int Mrows,
    const u16* __restrict__ B, int K, int Nrows,
    void* __restrict__ OUT, int ldo,
    const float* __restrict__ mask, int e0, int first,
    float* __restrict__ OUT2, const float* __restrict__ bias,
    size_t strideA, size_t strideB, size_t strideO, size_t strideO2)
{
    __shared__ u16 As[2][128][32];
    __shared__ u16 Bs[2][128][32];
    const int t  = threadIdx.x;
    const int ez = blockIdx.z;
    A += (size_t)ez * strideA;
    B += (size_t)ez * strideB;
    u16*   OUTu = (u16*)OUT + (size_t)ez * strideO;
    float* OUTf = (float*)OUT + (size_t)ez * strideO;
    if (MODE == 4) { OUT2 += (size_t)ez * strideO2; bias += (size_t)ez * NH; }
    const int nbx = gridDim.x;
    const int nwg = nbx * gridDim.y;
    int bid = blockIdx.y * nbx + blockIdx.x;
    {
        const int xcd = bid & 7, lo = bid >> 3;
        const int q8 = nwg >> 3, r8 = nwg & 7;
        bid = (xcd < r8 ? xcd*(q8+1) : r8*(q8+1) + (xcd - r8)*q8) + lo;
    }
    const int m0 = (bid / nbx) * 128;
    const int n0 = (bid % nbx) * 128;
    const int w  = t >> 6, l = t & 63;
    const int wm = (w >> 2) * 64, wn = (w & 3) * 32;
    const int sr = l >> 2;           // 0..15: row within wave's 16-row chunk
    const int sc = (l & 3) * 8;      // bf16 col 0,8,16,24

    f32x4 acc[4][2];
    #pragma unroll
    for (int i = 0; i < 4; ++i)
        #pragma unroll
        for (int j = 0; j < 2; ++j) {
            acc[i][j][0]=0.f; acc[i][j][1]=0.f; acc[i][j][2]=0.f; acc[i][j][3]=0.f;
        }

    const int nk = K >> 5;
    const int srow = w*16 + sr;
    {
        int ga = m0 + srow; if (ga >= Mrows) ga = Mrows - 1;
        gl16(A + (size_t)ga*lda + sc, &As[0][w*16][0]);
        int gb = n0 + srow; if (gb >= Nrows) gb = Nrows - 1;
        gl16(B + (size_t)gb*K + sc, &Bs[0][w*16][0]);
    }
    __syncthreads();

    for (int kt = 0; kt < nk; ++kt) {
        const int cur = kt & 1;
        if (kt + 1 < nk) {
            const int nxt = cur ^ 1;
            const int k0 = (kt + 1) << 5;
            int ga = m0 + srow; if (ga >= Mrows) ga = Mrows - 1;
            gl16(A + (size_t)ga*lda + k0 + sc, &As[nxt][w*16][0]);
            int gb = n0 + srow; if (gb >= Nrows) gb = Nrows - 1;
            gl16(B + (size_t)gb*K + k0 + sc, &Bs[nxt][w*16][0]);
        }
        {
            short8 af[4], bf[2];
            const int ko = (l >> 4)*8;
            #pragma unroll
            for (int i = 0; i < 4; ++i)
                af[i] = *(const short8*)&As[cur][wm + i*16 + (l & 15)][ko];
            #pragma unroll
            for (int j = 0; j < 2; ++j)
                bf[j] = *(const short8*)&Bs[cur][wn + j*16 + (l & 15)][ko];
            #pragma unroll
            for (int i = 0; i < 4; ++i)
                #pragma unroll
                for (int j = 0; j < 2; ++j)
                    acc[i][j] = __builtin_amdgcn_mfma_f32_16x16x32_bf16(
                        af[i], bf[j], acc[i][j], 0, 0, 0);
        }
        __syncthreads();
    }

    #pragma unroll
    for (int i = 0; i < 4; ++i) {
        #pragma unroll
        for (int r = 0; r < 4; ++r) {
            const int m = m0 + wm + i*16 + (l >> 4)*4 + r;
            if (m >= Mrows) continue;
            if (MODE == 2) {
                const float wgt = mask[m*4 + e0 + ez];
                #pragma unroll
                for (int j = 0; j < 2; ++j) {
                    const int n = n0 + wn + j*16 + (l & 15);
                    float* o = OUTf + (size_t)m*512 + n;
                    const float v = wgt * acc[i][j][r];
                    *o = first ? v : *o + v;
                }
            } else if (MODE == 5) {
                #pragma unroll
                for (int j = 0; j < 2; ++j) {
                    const int n = n0 + wn + j*16 + (l & 15);
                    OUTf[(size_t)m*512 + n] = acc[i][j][r];
                }
            } else if (MODE == 4) {
                #pragma unroll
                for (int j = 0; j < 2; ++j) {
                    const int n = n0 + wn + j*16 + (l & 15);
                    if (n < CONVD) {
                        OUTu[(size_t)m*ldo + n] = f2bf(acc[i][j][r]);
                    } else if (n < CONVD + NH) {
                        OUT2[(size_t)m*NH + (n - CONVD)] =
                            softplusf(acc[i][j][r] + bias[n - CONVD]);
                    }
                }
            } else {
                #pragma unroll
                for (int j = 0; j < 2; ++j) {
                    const int n = n0 + wn + j*16 + (l & 15);
                    OUTu[(size_t)m*ldo + n] = f2bf(acc[i][j][r]);
                }
            }
        }
    }
}

// ------------------------------------------------------------- combine -----
__global__ void __launch_bounds__(256) combine_kernel(
    const float* __restrict__ EO,    // NEXP x M x 512
    const float* __restrict__ mask,  // M x 4
    float* __restrict__ out)         // M x 512
{
    const int idx = blockIdx.x * 256 + threadIdx.x;
    const int m = idx >> 9;
    float s = 0.f;
    #pragma unroll
    for (int e = 0; e < NEXP; ++e)
        s += mask[m*4 + e] * EO[(size_t)e*S_EO + idx];
    out[idx] = s;
}

// ---------------------------------------- conv4 + SiLU, direct (no LDS) -----
__global__ void __launch_bounds__(256) conv_kernel(
    const u16* __restrict__ XBC,
    u16* __restrict__ XCONV,
    const float* __restrict__ conv_w,
    const float* __restrict__ conv_b,
    int e0)
{
    const int e = blockIdx.y;
    XBC   += (size_t)e * S_XC;
    XCONV += (size_t)e * S_XC;
    const int eg = e0 + e;
    const int idx = blockIdx.x * 256 + threadIdx.x;
    const int NCG = CONVD / 8;
    if (idx >= M_TOK * NCG) return;
    const int cg = idx % NCG;
    const int m  = idx / NCG;
    const int b  = m / L_SEQ, l = m - b*L_SEQ;
    const int c0 = cg * 8;

    const u16* base = XBC + (size_t)b*L_SEQ*CONVD + c0;
    const short8 z8 = {0,0,0,0,0,0,0,0};
    short8 r[4];
    #pragma unroll
    for (int k = 0; k < 4; ++k) {
        const int row = l - 3 + k;
        r[k] = (row >= 0) ? *(const short8*)(base + (size_t)row*CONVD) : z8;
    }
    const float4* wp = (const float4*)(conv_w + ((size_t)eg*CONVD + c0)*4);
    const float*  bp = conv_b + (size_t)eg*CONVD + c0;
    short8 o;
    #pragma unroll
    for (int j = 0; j < 8; ++j) {
        const float4 wj = wp[j];
        float v = bf2f(r[0][j])*wj.x + bf2f(r[1][j])*wj.y
                + bf2f(r[2][j])*wj.z + bf2f(r[3][j])*wj.w + bp[j];
        o[j] = f2bf(siluf(v));
    }
    *(short8*)(XCONV + (size_t)m*CONVD + c0) = o;
}

// --------------------------------------------------- SSD pass 1 (per chunk) -
// 16 waves; Bc/Cc/Xt col-XOR swizzled (key SWK(row), hoisted per thread/iter).
__global__ void __launch_bounds__(1024) ssd1_kernel(
    u16* __restrict__ XCONV,
    const float* __restrict__ DT,
    float* __restrict__ Acum,
    u16* __restrict__ Hend,
    float* __restrict__ cbuf,
    const float* __restrict__ A_log,
    const float* __restrict__ Dskip,
    int e0)
{
    const int g = blockIdx.x, h = blockIdx.y;
    const int bz = blockIdx.z;
    const int e = bz >> 2, b = bz & 3;
    XCONV += (size_t)e * S_XC;
    DT    += (size_t)e * S_DT;
    Acum  += (size_t)e * S_AC;
    Hend  += (size_t)e * S_HE;
    cbuf  += (size_t)e * S_CB;
    const int eg = e0 + e;
    const int t = threadIdx.x;
    const int ln = t & 63, w = t >> 6;
    const int rt = w >> 1;
    const int ch = w & 1;
    const int bh = b*NH + h;
    const int l0 = g * TCH;

    __shared__ u16 Bc[TCH][LPAD];
    __shared__ u16 Cc[TCH][LPAD];
    __shared__ u16 Xt[HD][LPAD];
    __shared__ u16 Pb[TCH][LPAD];
    __shared__ float ac[TCH], wj[TCH], dtb[TCH];

    const float Ah = -__expf(A_log[eg*NH + h]);
    const float Dv = Dskip[eg*NH + h];

    {   // stage: i = t>>3 (row for B/C, col for Xt), q = t&7
        const int i = t >> 3, q = t & 7;
        const bool v = (l0 + i) < L_SEQ;
        const u16* src = XCONV + (size_t)(b*L_SEQ + l0 + i) * CONVD;
        const short8 z8 = {0,0,0,0,0,0,0,0};
        const int kbc = SWK(i);          // per-thread const
        #pragma unroll
        for (int u = 0; u < 2; ++u) {
            const int col = q*16 + u*8;
            short8 bv = v ? *(const short8*)(src + 1024 + col) : z8;
            short8 cv = v ? *(const short8*)(src + 1152 + col) : z8;
            *(short8*)&Bc[i][col ^ kbc] = bv;
            *(short8*)&Cc[i][col ^ kbc] = cv;
        }
        {
            short8 xv = v ? *(const short8*)(src + h*HD + q*8) : z8;
            const int kx = q << 4;       // SWK(q*8+k) = q<<4, per-thread const
            const int cx = i ^ kx;
            #pragma unroll
            for (int k = 0; k < 8; ++k)
                Xt[q*8 + k][cx] = ((const u16*)&xv)[k];
        }
        if (t < TCH) {
            const int l = l0 + t;
            dtb[t] = (l < L_SEQ) ? DT[(size_t)(b*L_SEQ + l)*NH + h] : 0.f;
        }
    }
    __syncthreads();

    if (w == 0) {
        float s0 = dtb[ln] * Ah;
        float s1 = dtb[64 + ln] * Ah;
        #pragma unroll
        for (int o = 1; o < 64; o <<= 1) {
            float v0 = __shfl_up(s0, o);
            float v1 = __shfl_up(s1, o);
            if (ln >= o) { s0 += v0; s1 += v1; }
        }
        s1 += __shfl(s0, 63);
        const float acT = __shfl(s1, 63);
        ac[ln] = s0; ac[64 + ln] = s1;
        wj[ln]      = __expf(acT - s0) * dtb[ln];
        wj[64 + ln] = __expf(acT - s1) * dtb[64 + ln];
        if (l0 + ln < L_SEQ)      Acum[(size_t)bh*L_SEQ + l0 + ln] = s0;
        if (l0 + 64 + ln < L_SEQ) Acum[(size_t)bh*L_SEQ + l0 + 64 + ln] = s1;
        if (ln == 63) cbuf[bh*NC + g] = __expf(acT);
    }
    __syncthreads();

    // S = Cc @ Bc^T (swizzled reads)
    f32x4 sacc[4];
    #pragma unroll
    for (int c = 0; c < 4; ++c) { sacc[c][0]=0.f; sacc[c][1]=0.f; sacc[c][2]=0.f; sacc[c][3]=0.f; }
    {
        const int Ra = rt*16 + (ln & 15);
        const int ka = SWK(Ra);
        #pragma unroll
        for (int ks = 0; ks < 4; ++ks) {
            const int c0 = ks*32 + (ln >> 4)*8;
            short8 afr = *(const short8*)&Cc[Ra][c0 ^ ka];
            #pragma unroll
            for (int c = 0; c < 4; ++c) {
                const int Rb = (ch*4 + c)*16 + (ln & 15);
                short8 bfr = *(const short8*)&Bc[Rb][c0 ^ SWK(Rb)];
                sacc[c] = __builtin_amdgcn_mfma_f32_16x16x32_bf16(afr, bfr, sacc[c], 0, 0, 0);
            }
        }
    }
    // P (Pb unswizzled)
    {
        const int i0 = rt*16 + (ln >> 4)*4;
        float aci[4];
        #pragma unroll
        for (int r = 0; r < 4; ++r) aci[r] = ac[i0 + r];
        #pragma unroll
        for (int c = 0; c < 4; ++c) {
            const int j = (ch*4 + c)*16 + (ln & 15);
            const float acj = ac[j], dtj = dtb[j];
            #pragma unroll
            for (int r = 0; r < 4; ++r) {
                const int i2 = i0 + r;
                float pv = (j <= i2) ? sacc[c][r] * __expf(aci[r] - acj) * dtj : 0.f;
                Pb[i2][j] = f2bf(pv);
            }
        }
    }
    __syncthreads();

    // Y1 = P @ X (+ D*x)
    {
        f32x4 yacc[2];
        #pragma unroll
        for (int p = 0; p < 2; ++p) { yacc[p][0]=0.f; yacc[p][1]=0.f; yacc[p][2]=0.f; yacc[p][3]=0.f; }
        #pragma unroll
        for (int ks = 0; ks < 4; ++ks) {
            const int c0 = ks*32 + (ln >> 4)*8;
            short8 afr = *(const short8*)&Pb[rt*16 + (ln & 15)][c0];
            #pragma unroll
            for (int p = 0; p < 2; ++p) {
                const int Rx = (ch*2 + p)*16 + (ln & 15);
                short8 bfr = *(const short8*)&Xt[Rx][c0 ^ SWK(Rx)];
                yacc[p] = __builtin_amdgcn_mfma_f32_16x16x32_bf16(afr, bfr, yacc[p], 0, 0, 0);
            }
        }
        #pragma unroll
        for (int p = 0; p < 2; ++p) {
            const int pp = (ch*2 + p)*16 + (ln & 15);
            const int kp = SWK(pp);
            #pragma unroll
            for (int r = 0; r < 4; ++r) {
                const int i2 = rt*16 + (ln >> 4)*4 + r;
                const int lg = l0 + i2;
                if (lg < L_SEQ) {
                    const float xv = bf2f(Xt[pp][i2 ^ kp]);
                    XCONV[(size_t)(b*L_SEQ + lg)*CONVD + h*HD + pp] =
                        f2bf(yacc[p][r] + Dv * xv);
                }
            }
        }
    }

    // Hloc = (Bc^T * wj) @ X
    {
        f32x4 hacc[2];
        #pragma unroll
        for (int p = 0; p < 2; ++p) { hacc[p][0]=0.f; hacc[p][1]=0.f; hacc[p][2]=0.f; hacc[p][3]=0.f; }
        const int nr = rt*16 + (ln & 15);
        #pragma unroll
        for (int ks = 0; ks < 4; ++ks) {
            const int jb = ks*32 + (ln >> 4)*8;
            const int nrs = nr ^ SWK(jb);     // (jb+jj)>>3 == jb>>3 for jj<8
            short8 afr;
            #pragma unroll
            for (int jj = 0; jj < 8; ++jj)
                afr[jj] = (short)f2bf(bf2f(Bc[jb + jj][nrs]) * wj[jb + jj]);
            #pragma unroll
            for (int p = 0; p < 2; ++p) {
                const int Rx = (ch*2 + p)*16 + (ln & 15);
                short8 bfr = *(const short8*)&Xt[Rx][jb ^ SWK(Rx)];
                hacc[p] = __builtin_amdgcn_mfma_f32_16x16x32_bf16(afr, bfr, hacc[p], 0, 0, 0);
            }
        }
        u16* Hb = Hend + (size_t)(bh*NC + g) * (TCH*HD);
        #pragma unroll
        for (int p = 0; p < 2; ++p)
            #pragma unroll
            for (int r = 0; r < 4; ++r) {
                const int n = rt*16 + (ln >> 4)*4 + r;
                Hb[n*HD + (ch*2 + p)*16 + (ln & 15)] = f2bf(hacc[p][r]);
            }
    }
}

// --------------------------------------- pass 2: chunk-state propagation ----
__global__ void __launch_bounds__(256) prop_kernel(
    u16* __restrict__ Hend, const float* __restrict__ cbuf)
{
    const int e  = blockIdx.x >> 6;
    const int bh = blockIdx.x & 63;
    Hend += (size_t)e * S_HE;
    cbuf += (size_t)e * S_CB;
    const int t  = threadIdx.x;
    float hs[32];
    #pragma unroll
    for (int j = 0; j < 32; ++j) hs[j] = 0.f;
    for (int g = 0; g < NC - 1; ++g) {
        const float ce = cbuf[bh*NC + g];
        u16* He = Hend + (size_t)(bh*NC + g)*(TCH*HD) + t*32;
        #pragma unroll
        for (int j = 0; j < 32; ++j) {
            const float lo = bf2f(He[j]);
            hs[j] = ce*hs[j] + lo;
            He[j] = f2bf(hs[j]);
        }
    }
}

// --------------------------------------------- pass 3: Y2 = Cs @ h_start ----
__global__ void __launch_bounds__(256) ssd2_kernel(
    u16* __restrict__ XCONV,
    const float* __restrict__ Acum,
    const u16* __restrict__ Hend)
{
    const int g = blockIdx.x + 1, h = blockIdx.y;
    const int bz = blockIdx.z;
    const int e = bz >> 2, b = bz & 3;
    XCONV += (size_t)e * S_XC;
    Acum  += (size_t)e * S_AC;
    Hend  += (size_t)e * S_HE;
    const int t = threadIdx.x, ln = t & 63, w = t >> 6;
    const int bh = b*NH + h;
    const int l0 = g * TCH;

    __shared__ u16 Cs[TCH][LPAD];
    __shared__ u16 Ht[HD][LPAD];

    {
        const int i = t >> 1, q = t & 1;
        const bool v = (l0 + i) < L_SEQ;
        const float eaci = v ? __expf(Acum[(size_t)bh*L_SEQ + l0 + i]) : 0.f;
        const u16* src = XCONV + (size_t)(b*L_SEQ + l0 + i)*CONVD + 1152 + q*64;
        const short8 z8 = {0,0,0,0,0,0,0,0};
        #pragma unroll
        for (int u = 0; u < 8; ++u) {
            short8 cv = v ? *(const short8*)(src + u*8) : z8;
            short8 ov;
            #pragma unroll
            for (int k = 0; k < 8; ++k)
                ov[k] = (short)f2bf(bf2f(((const u16*)&cv)[k]) * eaci);
            *(short8*)&Cs[i][q*64 + u*8] = ov;
        }
    }
    {
        const u16* Hb = Hend + (size_t)(bh*NC + g - 1)*(TCH*HD) + t*32;
        #pragma unroll
        for (int k = 0; k < 32; ++k) {
            const int idx = t*32 + k;
            Ht[idx & 63][idx >> 6] = Hb[k];
        }
    }
    __syncthreads();

    f32x4 acc2[2][4];
    #pragma unroll
    for (int rt = 0; rt < 2; ++rt)
        #pragma unroll
        for (int pt = 0; pt < 4; ++pt) { acc2[rt][pt][0]=0.f; acc2[rt][pt][1]=0.f; acc2[rt][pt][2]=0.f; acc2[rt][pt][3]=0.f; }
    #pragma unroll
    for (int ks = 0; ks < 4; ++ks) {
        short8 af0 = *(const short8*)&Cs[w*32 +      (ln & 15)][ks*32 + (ln >> 4)*8];
        short8 af1 = *(const short8*)&Cs[w*32 + 16 + (ln & 15)][ks*32 + (ln >> 4)*8];
        #pragma unroll
        for (int pt = 0; pt < 4; ++pt) {
            short8 bfr = *(const short8*)&Ht[pt*16 + (ln & 15)][ks*32 + (ln >> 4)*8];
            acc2[0][pt] = __builtin_amdgcn_mfma_f32_16x16x32_bf16(af0, bfr, acc2[0][pt], 0, 0, 0);
            acc2[1][pt] = __builtin_amdgcn_mfma_f32_16x16x32_bf16(af1, bfr, acc2[1][pt], 0, 0, 0);
        }
    }
    #pragma unroll
    for (int rt = 0; rt < 2; ++rt)
        #pragma unroll
        for (int pt = 0; pt < 4; ++pt)
            #pragma unroll
            for (int r = 0; r < 4; ++r) {
                const int i2 = w*32 + rt*16 + (ln >> 4)*4 + r;
                const int lg = l0 + i2;
                if (lg < L_SEQ) {
                    u16* yp = XCONV + (size_t)(b*L_SEQ + lg)*CONVD + h*HD + pt*16 + (ln & 15);
                    *yp = f2bf(bf2f(*yp) + acc2[rt][pt][r]);
                }
            }
}

// ------------------------------------------------- gated RMS norm (bf16) ----
__global__ void __launch_bounds__(256) norm_kernel(
    u16* __restrict__ Ybuf,
    const u16* __restrict__ Z,
    const float* __restrict__ norm_w,
    int e0)
{
    const int e = blockIdx.y;
    Ybuf += (size_t)e * S_XC;
    Z    += (size_t)e * S_ZT;
    const float* nw = norm_w + (size_t)(e0 + e) * DINNER;
    const int row = blockIdx.x;
    const int t = threadIdx.x;
    u16* y = Ybuf + (size_t)row * CONVD;
    const u16* z = Z + (size_t)row * DINNER;

    ushort4 yv = *(const ushort4*)(y + t*4);
    ushort4 zv = *(const ushort4*)(z + t*4);
    float v[4]; float ss = 0.f;
    #pragma unroll
    for (int j = 0; j < 4; ++j) {
        const float zz = bf2f(((const u16*)&zv)[j]);
        const float vv = bf2f(((const u16*)&yv)[j]) * siluf(zz);
        v[j] = vv; ss += vv*vv;
    }
    #pragma unroll
    for (int o = 32; o > 0; o >>= 1) ss += __shfl_down(ss, o);
    __shared__ float wsum[4];
    if ((t & 63) == 0) wsum[t >> 6] = ss;
    __syncthreads();
    const float total = wsum[0] + wsum[1] + wsum[2] + wsum[3];
    const float scale = rsqrtf(total / (float)DINNER + 1e-5f);
    ushort4 ov;
    #pragma unroll
    for (int j = 0; j < 4; ++j)
        ((u16*)&ov)[j] = f2bf(v[j] * scale * nw[t*4 + j]);
    *(ushort4*)(y + t*4) = ov;
}

// ------------------------------------------------------------------ host ----
extern "C" void kernel_launch(void* const* d_in, const int* in_sizes, int n_in,
                              void* d_out, int out_size, void* d_ws, size_t ws_size,
                              hipStream_t stream)
{
    const float* x        = (const float*)d_in[0];
    const float* gate_w   = (const float*)d_in[1];
    const float* gate_b   = (const float*)d_in[2];
    const float* gate_n   = (const float*)d_in[3];
    const float* in_w     = (const float*)d_in[4];
    const float* conv_w   = (const float*)d_in[5];
    const float* conv_b   = (const float*)d_in[6];
    const float* dt_bias  = (const float*)d_in[7];
    const float* A_log    = (const float*)d_in[8];
    const float* Dskip    = (const float*)d_in[9];
    const float* norm_w   = (const float*)d_in[10];
    const float* out_w    = (const float*)d_in[11];
    float* out = (float*)d_out;

    char* ws = (char*)d_ws;
    const size_t NEED_BIG = 189969408;
    const bool big = ws_size >= NEED_BIG;

    if (big) {
        // R1 serves sequentially: XBCraw_all -> Hend_all -> Ztile_all -> EO_all
        u16*   R1     = (u16*)ws;                        //  81,920,000 B
        u16*   XCONV  = (u16*)(ws + 81920000);           //  81,920,000 B
        u16*   xbf    = (u16*)(ws + 163840000);          //   8,192,000 B
        u16*   inwb   = (u16*)(ws + 172032000);          //   9,502,720 B
        u16*   outwb  = (u16*)(ws + 181534720);          //   4,194,304 B
        float* DTb    = (float*)(ws + 185729024);        //   2,048,000 B
        float* Acum   = (float*)(ws + 187777024);        //   2,048,000 B
        float* cbuf   = (float*)(ws + 189825024);        //      16,384 B
        float* maskb  = (float*)(ws + 189841408);        //     128,000 B
        float* EO     = (float*)R1;                      //  65,536,000 B (alias)

        gate_kernel<<<M_TOK, 64, 0, stream>>>(x, gate_w, gate_b, gate_n, maskb);
        cvt_kernel<<<2000, 256, 0, stream>>>(x, xbf, 512000);
        cvt_kernel<<<2320, 256, 0, stream>>>(in_w, inwb, 593920);
        cvt_kernel<<<1024, 256, 0, stream>>>(out_w, outwb, 262144);

        gemm_bb<4><<<dim3(11, 63, NEXP), 512, 0, stream>>>(
            xbf, DMODEL, M_TOK, inwb + (size_t)1024*512, DMODEL, 1296,
            R1, CONVD, nullptr, 0, 0, DTb, dt_bias, 0, S_WI, S_XC, S_DT);
        conv_kernel<<<dim3(5000, NEXP), 256, 0, stream>>>(
            R1, XCONV, conv_w, conv_b, 0);
        ssd1_kernel<<<dim3(NC, NH, BATCH*NEXP), 1024, 0, stream>>>(
            XCONV, DTb, Acum, (u16*)R1, cbuf, A_log, Dskip, 0);
        prop_kernel<<<64*NEXP, 256, 0, stream>>>((u16*)R1, cbuf);
        ssd2_kernel<<<dim3(NC - 1, NH, BATCH*NEXP), 256, 0, stream>>>(
            XCONV, Acum, (const u16*)R1);
        gemm_bb<0><<<dim3(8, 63, NEXP), 512, 0, stream>>>(
            xbf, DMODEL, M_TOK, inwb, DMODEL, DINNER,
            R1, DINNER, nullptr, 0, 0, nullptr, nullptr, 0, S_WI, S_ZT, 0);
        norm_kernel<<<dim3(M_TOK, NEXP), 256, 0, stream>>>(
            XCONV, R1, norm_w, 0);
        // out_proj: batched into EO (R1 dead after norm), then combine.
        gemm_bb<5><<<dim3(4, 63, NEXP), 512, 0, stream>>>(
            XCONV, CONVD, M_TOK, outwb, DINNER, DMODEL,
            EO, 512, nullptr, 0, 0, nullptr, nullptr, S_XC, S_WO, S_EO, 0);
        combine_kernel<<<M_TOK*DMODEL/256, 256, 0, stream>>>(EO, maskb, out);
    } else {
        // fallback: per-expert loop (64MB layout)
        u16*   R1     = (u16*)ws;
        u16*   XCONV  = (u16*)(ws + 20480000);
        u16*   xbf    = (u16*)(ws + 40960000);
        u16*   inwb   = (u16*)(ws + 49152000);
        u16*   outwb  = (u16*)(ws + 58654720);
        float* DTb    = (float*)(ws + 62849024);
        float* Acum   = (float*)(ws + 63361024);
        float* cbuf   = (float*)(ws + 63873024);
        float* maskb  = (float*)(ws + 63877120);

        gate_kernel<<<M_TOK, 64, 0, stream>>>(x, gate_w, gate_b, gate_n, maskb);
        cvt_kernel<<<2000, 256, 0, stream>>>(x, xbf, 512000);
        cvt_kernel<<<2320, 256, 0, stream>>>(in_w, inwb, 593920);
        cvt_kernel<<<1024, 256, 0, stream>>>(out_w, outwb, 262144);

        for (int e = 0; e < NEXP; ++e) {
            gemm_bb<4><<<dim3(11, 63, 1), 512, 0, stream>>>(
                xbf, DMODEL, M_TOK,
                inwb + (size_t)e*S_WI + (size_t)1024*512, DMODEL, 1296,
                R1, CONVD, nullptr, 0, 0, DTb, dt_bias + e*NH, 0, 0, 0, 0);
            conv_kernel<<<dim3(5000, 1), 256, 0, stream>>>(
                R1, XCONV, conv_w, conv_b, e);
            ssd1_kernel<<<dim3(NC, NH, BATCH), 1024, 0, stream>>>(
                XCONV, DTb, Acum, (u16*)R1, cbuf, A_log, Dskip, e);
            prop_kernel<<<64, 256, 0, stream>>>((u16*)R1, cbuf);
            ssd2_kernel<<<dim3(NC - 1, NH, BATCH), 256, 0, stream>>>(
                XCONV, Acum, (const u16*)R1);
            gemm_bb<0><<<dim3(8, 63, 1), 512, 0, stream>>>(
                xbf, DMODEL, M_TOK, inwb + (size_t)e*S_WI, DMODEL, DINNER,
                R1, DINNER, nullptr, 0, 0, nullptr, nullptr, 0, 0, 0, 0);
            norm_kernel<<<dim3(M_TOK, 1), 256, 0, stream>>>(
                XCONV, R1, norm_w, e);
            gemm_bb<2><<<dim3(4, 63, 1), 512, 0, stream>>>(
                XCONV, CONVD, M_TOK, outwb + (size_t)e*S_WO, DINNER, DMODEL,
                out, 512, maskb, e, e == 0 ? 1 : 0, nullptr, nullptr, 0, 0, 0, 0);
        }
    }
}